// Round 7
// baseline (1969.310 us; speedup 1.0000x reference)
//
#include <hip/hip_runtime.h>

typedef __attribute__((ext_vector_type(4))) float f4;
typedef __attribute__((ext_vector_type(8))) short bfx8;
typedef __attribute__((ext_vector_type(4))) float f32x4;
typedef __attribute__((ext_vector_type(4))) unsigned int u32x4;
typedef __attribute__((ext_vector_type(4))) unsigned short u16x4;
typedef unsigned short ushort_t;

#define DM 768
#define DINNER 1536
#define NH 24
#define XBCW 1664
#define DINPROJ 3224
#define NCHUNK 64
#define BROWS 8192
#define PAD 68  // LDS row stride (floats) for 64-wide tiles

__device__ inline ushort_t f2bf(float f) {
    unsigned u = __builtin_bit_cast(unsigned, f);
    unsigned r = (u + 0x7FFF + ((u >> 16) & 1)) >> 16;
    return (ushort_t)r;
}
__device__ inline float bf2f(ushort_t u) {
    return __builtin_bit_cast(float, (unsigned)u << 16);
}
__device__ inline u32x4 pack8(f4 a, f4 b) {
    u32x4 o;
    o[0] = (unsigned)f2bf(a[0]) | ((unsigned)f2bf(a[1]) << 16);
    o[1] = (unsigned)f2bf(a[2]) | ((unsigned)f2bf(a[3]) << 16);
    o[2] = (unsigned)f2bf(b[0]) | ((unsigned)f2bf(b[1]) << 16);
    o[3] = (unsigned)f2bf(b[2]) | ((unsigned)f2bf(b[3]) << 16);
    return o;
}

__global__ __launch_bounds__(256) void fill_kernel(float* out, int n, float v) {
    int i = blockIdx.x * 256 + threadIdx.x;
    if (i < n) out[i] = v;
}

// ---- GEMM C = A[M][K] * B[N][K]^T (B f32, staged to bf16).
// EPI=0: A bf16, C f32 dense (out-proj). EPI=1: A f32 (u), split epilogue (in-proj).
template <int EPI>
__global__ __launch_bounds__(256) void gemm_bt(const void* __restrict__ Ap,
                                               const float* __restrict__ B,
                                               float* __restrict__ C,
                                               int K, int ldc, int nrowsB,
                                               ushort_t* __restrict__ zbf,
                                               float* __restrict__ xbcraw,
                                               float* __restrict__ dtbT,
                                               const float* __restrict__ dt_bias) {
    __shared__ __align__(16) ushort_t As[128 * 32];
    __shared__ __align__(16) ushort_t Bs[128 * 32];
    int tid = threadIdx.x;
    int lane = tid & 63;
    int w = tid >> 6;
    int wr = w >> 1, wc = w & 1;
    int m0 = blockIdx.y * 128;
    int n0 = blockIdx.x * 128;
    int r16 = lane & 15, kg = lane >> 4;

    f32x4 acc[4][4] = {};

    for (int k0 = 0; k0 < K; k0 += 32) {
        u32x4 av[2], bv[2];
#pragma unroll
        for (int r = 0; r < 2; ++r) {
            int chunk = tid + 256 * r;
            int row = chunk >> 2, cof = (chunk & 3) * 8;
            if (EPI == 1) {
                const float* A = (const float*)Ap;
                f4 a0 = *(const f4*)&A[(long)(m0 + row) * K + k0 + cof];
                f4 a1 = *(const f4*)&A[(long)(m0 + row) * K + k0 + cof + 4];
                av[r] = pack8(a0, a1);
            } else {
                const ushort_t* A = (const ushort_t*)Ap;
                av[r] = *(const u32x4*)&A[(long)(m0 + row) * K + k0 + cof];
            }
            int br = n0 + row;
            if (br < nrowsB) {
                f4 b0 = *(const f4*)&B[(long)br * K + k0 + cof];
                f4 b1 = *(const f4*)&B[(long)br * K + k0 + cof + 4];
                bv[r] = pack8(b0, b1);
            } else {
                bv[r] = (u32x4){0, 0, 0, 0};
            }
        }
        __syncthreads();
#pragma unroll
        for (int r = 0; r < 2; ++r) {
            int chunk = tid + 256 * r;
            int row = chunk >> 2, cof = (chunk & 3) * 8;
            *(u32x4*)&As[row * 32 + cof] = av[r];
            *(u32x4*)&Bs[row * 32 + cof] = bv[r];
        }
        __syncthreads();
        bfx8 af[4], bfr[4];
#pragma unroll
        for (int i = 0; i < 4; ++i) {
            af[i] = *(const bfx8*)&As[(wr * 64 + i * 16 + r16) * 32 + kg * 8];
            bfr[i] = *(const bfx8*)&Bs[(wc * 64 + i * 16 + r16) * 32 + kg * 8];
        }
#pragma unroll
        for (int i = 0; i < 4; ++i)
#pragma unroll
            for (int j = 0; j < 4; ++j)
                acc[i][j] = __builtin_amdgcn_mfma_f32_16x16x32_bf16(af[i], bfr[j], acc[i][j], 0, 0, 0);
    }

#pragma unroll
    for (int i = 0; i < 4; ++i) {
        int rowb = m0 + wr * 64 + i * 16 + kg * 4;
#pragma unroll
        for (int j = 0; j < 4; ++j) {
            int col = n0 + wc * 64 + j * 16 + r16;
            if (EPI == 0) {
#pragma unroll
                for (int q = 0; q < 4; ++q)
                    C[(long)(rowb + q) * ldc + col] = acc[i][j][q];
            } else {
                if (n0 < DINNER) {  // z -> bf16
#pragma unroll
                    for (int q = 0; q < 4; ++q)
                        zbf[(long)(rowb + q) * DINNER + col] = f2bf(acc[i][j][q]);
                } else if (n0 < 3200) {  // xBC raw -> f32
#pragma unroll
                    for (int q = 0; q < 4; ++q)
                        xbcraw[(long)(rowb + q) * XBCW + col - DINNER] = acc[i][j][q];
                } else if (col < DINPROJ) {  // dt -> softplus -> transposed
                    int h = col - 3200;
                    float bias = dt_bias[h];
#pragma unroll
                    for (int q = 0; q < 4; ++q) {
                        float v = acc[i][j][q] + bias;
                        float d = (v > 20.f) ? v : log1pf(__expf(v));
                        dtbT[(long)h * BROWS + rowb + q] = d;
                    }
                }
            }
        }
    }
}

// ---- depthwise causal conv(4) + bias + silu (dense in/out) ----
__global__ __launch_bounds__(256) void conv_kernel(const float* __restrict__ xin,
                                                   const float* __restrict__ cw,
                                                   const float* __restrict__ cb,
                                                   float* __restrict__ xbc) {
    int ch = blockIdx.y * 256 + threadIdx.x;
    int row = blockIdx.x;
    if (ch >= XBCW) return;
    int b = row >> 12;
    int l = row & 4095;
    float acc = cb[ch];
#pragma unroll
    for (int k = 0; k < 4; ++k) {
        int ll = l - 3 + k;
        if (ll >= 0)
            acc += cw[ch * 4 + k] * xin[(long)(b * 4096 + ll) * XBCW + ch];
    }
    float s = acc / (1.f + __expf(-acc));
    xbc[(long)row * XBCW + ch] = s;
}

// ---- per-chunk cumsum of A*dt via wave scan ----
__global__ __launch_bounds__(256) void acs_kernel(const float* __restrict__ dtbT,
                                                  const float* __restrict__ A_log,
                                                  float* __restrict__ acs,
                                                  float* __restrict__ Tsum) {
    int bh = blockIdx.x;  // b*24+h
    int b = bh / NH, h = bh % NH;
    int t = threadIdx.x;
    int lane = t & 63;
    float A = -__expf(A_log[h]);
    const float* dp = &dtbT[(long)h * BROWS + b * 4096];
#pragma unroll
    for (int it = 0; it < 16; ++it) {
        int c = (t >> 6) + 4 * it;
        float v = A * dp[c * 64 + lane];
#pragma unroll
        for (int off = 1; off < 64; off <<= 1) {
            float u = __shfl_up(v, off, 64);
            if (lane >= off) v += u;
        }
        acs[((long)bh * NCHUNK + c) * 64 + lane] = v;
        if (lane == 63) Tsum[bh * NCHUNK + c] = v;
    }
}

// ---- phase A: per-chunk states[p][n] -> bf16 ----
__global__ __launch_bounds__(256) void states_kernel(const float* __restrict__ xbc,
                                                     const float* __restrict__ dtbT,
                                                     const float* __restrict__ acs,
                                                     const float* __restrict__ Tsum,
                                                     ushort_t* __restrict__ states) {
    int h = blockIdx.x, c = blockIdx.y, b = blockIdx.z;
    __shared__ __align__(16) float sW[64 * PAD];
    __shared__ __align__(16) float sB[64 * PAD];
    __shared__ float sWt[64];
    int t = threadIdx.x;
    long rowg0 = (long)b * 4096 + c * 64;
    long acsb = ((long)(b * NH + h) * NCHUNK + c) * 64;
    float T = Tsum[(b * NH + h) * NCHUNK + c];
    if (t < 64)
        sWt[t] = dtbT[(long)h * BROWS + rowg0 + t] * __expf(T - acs[acsb + t]);
    __syncthreads();
#pragma unroll
    for (int i = 0; i < 4; ++i) {
        int q = t + 256 * i;
        int l = q >> 4, m = q & 15;
        const float* rp = &xbc[(rowg0 + l) * (long)XBCW];
        f4 gx = *(const f4*)&rp[h * 64 + 4 * m];
        float wt = sWt[l];
        gx[0] *= wt; gx[1] *= wt; gx[2] *= wt; gx[3] *= wt;
        *(f4*)&sW[l * PAD + 4 * m] = gx;
        f4 gb = *(const f4*)&rp[DINNER + 4 * m];
        *(f4*)&sB[l * PAD + 4 * m] = gb;
    }
    __syncthreads();
    int p0 = (t >> 4) * 4, n0 = (t & 15) * 4;
    float acc[4][4] = {};
    for (int l4 = 0; l4 < 16; ++l4) {
#pragma unroll
        for (int qq = 0; qq < 4; ++qq) {
            int l = 4 * l4 + qq;
            f4 wv = *(const f4*)&sW[l * PAD + p0];
            f4 bv = *(const f4*)&sB[l * PAD + n0];
#pragma unroll
            for (int i = 0; i < 4; ++i)
#pragma unroll
                for (int j = 0; j < 4; ++j)
                    acc[i][j] += wv[i] * bv[j];
        }
    }
    long ob = ((long)(b * NH + h) * NCHUNK + c) * 4096;
#pragma unroll
    for (int i = 0; i < 4; ++i) {
        u16x4 o;
#pragma unroll
        for (int j = 0; j < 4; ++j) o[j] = f2bf(acc[i][j]);
        *(u16x4*)&states[ob + (p0 + i) * 64 + n0] = o;
    }
}

// ---- sequential chunk scan ----
__global__ __launch_bounds__(256) void scan_kernel(const float* __restrict__ Tsum,
                                                   ushort_t* __restrict__ states) {
    int e = blockIdx.x * 256 + threadIdx.x;
    int h = blockIdx.y, b = blockIdx.z;
    long base = ((long)(b * NH + h)) * NCHUNK * 4096 + e;
    const float* Tp = &Tsum[(b * NH + h) * NCHUNK];
    float acc = 0.f;
    for (int c = 0; c < NCHUNK; ++c) {
        float cur = bf2f(states[base + (long)c * 4096]);
        states[base + (long)c * 4096] = f2bf(acc);
        acc = __expf(Tp[c]) * acc + cur;
    }
}

// ---- phase C: Y -> dense bf16 ybuf ----
__global__ __launch_bounds__(256, 3) void yfull_kernel(const float* __restrict__ xbc,
                                                       const float* __restrict__ dtbT,
                                                       const float* __restrict__ acs,
                                                       const ushort_t* __restrict__ sprev,
                                                       ushort_t* __restrict__ ybuf) {
    int h = blockIdx.x, c = blockIdx.y, b = blockIdx.z;
    __shared__ __align__(16) float bufC[64 * PAD];  // C[l][n]
    __shared__ __align__(16) float bufX[64 * PAD];  // BT[n][s] -> xd[s][p] -> sprevT[n][p]
    __shared__ __align__(16) float bufS[64 * PAD];  // scores[l][s]
    __shared__ float sAcs[64], sE[64], sDt[64];
    int t = threadIdx.x;
    long rowg0 = (long)b * 4096 + c * 64;
    long acsb = ((long)(b * NH + h) * NCHUNK + c) * 64;
    if (t < 64) {
        float a = acs[acsb + t];
        sAcs[t] = a;
        sE[t] = __expf(a);
        sDt[t] = dtbT[(long)h * BROWS + rowg0 + t];
    }
    // stage C dense, B transposed
#pragma unroll
    for (int i = 0; i < 4; ++i) {
        int q = t + 256 * i;
        int l = q >> 4, m = q & 15;
        const float* rp = &xbc[(rowg0 + l) * (long)XBCW];
        f4 gC = *(const f4*)&rp[1600 + 4 * m];
        *(f4*)&bufC[l * PAD + 4 * m] = gC;
        f4 gB = *(const f4*)&rp[DINNER + 4 * m];
        bufX[(4 * m + 0) * PAD + l] = gB[0];
        bufX[(4 * m + 1) * PAD + l] = gB[1];
        bufX[(4 * m + 2) * PAD + l] = gB[2];
        bufX[(4 * m + 3) * PAD + l] = gB[3];
    }
    __syncthreads();
    int l0 = (t >> 4) * 4, s0 = (t & 15) * 4;
    // phase 1: sc = C.B^T
    float acc[4][4] = {};
    for (int n4 = 0; n4 < 16; ++n4) {
        f4 cv[4];
#pragma unroll
        for (int i = 0; i < 4; ++i) cv[i] = *(const f4*)&bufC[(l0 + i) * PAD + 4 * n4];
#pragma unroll
        for (int qq = 0; qq < 4; ++qq) {
            f4 bq = *(const f4*)&bufX[(4 * n4 + qq) * PAD + s0];
#pragma unroll
            for (int i = 0; i < 4; ++i)
#pragma unroll
                for (int j = 0; j < 4; ++j)
                    acc[i][j] += cv[i][qq] * bq[j];
        }
    }
    __syncthreads();  // all BT reads done
    // mask+decay -> bufS; stage xd into bufX
#pragma unroll
    for (int i = 0; i < 4; ++i) {
        int l = l0 + i;
        f4 o;
#pragma unroll
        for (int j = 0; j < 4; ++j) {
            int s = s0 + j;
            o[j] = (s <= l) ? acc[i][j] * __expf(sAcs[l] - sAcs[s]) : 0.f;
        }
        *(f4*)&bufS[l * PAD + s0] = o;
    }
#pragma unroll
    for (int i = 0; i < 4; ++i) {
        int q = t + 256 * i;
        int l = q >> 4, m = q & 15;
        f4 gx = *(const f4*)&xbc[(rowg0 + l) * (long)XBCW + h * 64 + 4 * m];
        float d = sDt[l];
        gx[0] *= d; gx[1] *= d; gx[2] *= d; gx[3] *= d;
        *(f4*)&bufX[l * PAD + 4 * m] = gx;
    }
    __syncthreads();
    // phase 2: yd = S.xd
    float yd[4][4] = {};
    for (int s4 = 0; s4 < 16; ++s4) {
        f4 sv[4];
#pragma unroll
        for (int i = 0; i < 4; ++i) sv[i] = *(const f4*)&bufS[(l0 + i) * PAD + 4 * s4];
#pragma unroll
        for (int qq = 0; qq < 4; ++qq) {
            f4 xq = *(const f4*)&bufX[(4 * s4 + qq) * PAD + s0];
#pragma unroll
            for (int i = 0; i < 4; ++i)
#pragma unroll
                for (int j = 0; j < 4; ++j)
                    yd[i][j] += sv[i][qq] * xq[j];
        }
    }
    __syncthreads();  // xd reads done
    // stage sprev transposed
    long spb = ((long)(b * NH + h) * NCHUNK + c) * 4096;
#pragma unroll
    for (int i = 0; i < 4; ++i) {
        int q = t + 256 * i;
        int p = q >> 4, m = q & 15;
        u16x4 gs = *(const u16x4*)&sprev[spb + p * 64 + 4 * m];
        bufX[(4 * m + 0) * PAD + p] = bf2f(gs[0]);
        bufX[(4 * m + 1) * PAD + p] = bf2f(gs[1]);
        bufX[(4 * m + 2) * PAD + p] = bf2f(gs[2]);
        bufX[(4 * m + 3) * PAD + p] = bf2f(gs[3]);
    }
    __syncthreads();
    // phase 3: yo = C.Sprev^T
    float yo[4][4] = {};
    for (int n4 = 0; n4 < 16; ++n4) {
        f4 cv[4];
#pragma unroll
        for (int i = 0; i < 4; ++i) cv[i] = *(const f4*)&bufC[(l0 + i) * PAD + 4 * n4];
#pragma unroll
        for (int qq = 0; qq < 4; ++qq) {
            f4 pq = *(const f4*)&bufX[(4 * n4 + qq) * PAD + s0];
#pragma unroll
            for (int i = 0; i < 4; ++i)
#pragma unroll
                for (int j = 0; j < 4; ++j)
                    yo[i][j] += cv[i][qq] * pq[j];
        }
    }
    // epilogue: dense bf16
#pragma unroll
    for (int i = 0; i < 4; ++i) {
        int l = l0 + i;
        u16x4 o;
#pragma unroll
        for (int j = 0; j < 4; ++j) o[j] = f2bf(yd[i][j] + sE[l] * yo[i][j]);
        *(u16x4*)&ybuf[(rowg0 + l) * (long)DINNER + h * 64 + s0] = o;
    }
}

// ---- gated RMS norm -> bf16 ----
__global__ __launch_bounds__(256) void norm_kernel(const ushort_t* __restrict__ ybuf,
                                                   const float* __restrict__ xbc,
                                                   const ushort_t* __restrict__ zbf,
                                                   const float* __restrict__ Dp,
                                                   const float* __restrict__ normw,
                                                   ushort_t* __restrict__ ybf) {
    int row = blockIdx.x;
    int t = threadIdx.x;
    float g[6];
    float ss = 0.f;
#pragma unroll
    for (int i = 0; i < 6; ++i) {
        int j = t + 256 * i;
        int h = j >> 6;
        float x = xbc[(long)row * XBCW + j];
        float yy = bf2f(ybuf[(long)row * DINNER + j]) + x * Dp[h];
        float z = bf2f(zbf[(long)row * DINNER + j]);
        float gz = z / (1.f + __expf(-z));
        float v = yy * gz;
        g[i] = v;
        ss += v * v;
    }
#pragma unroll
    for (int o = 32; o > 0; o >>= 1) ss += __shfl_xor(ss, o, 64);
    __shared__ float wsum[4];
    __shared__ float sscale;
    int w = t >> 6;
    if ((t & 63) == 0) wsum[w] = ss;
    __syncthreads();
    if (t == 0) {
        float tot = wsum[0] + wsum[1] + wsum[2] + wsum[3];
        sscale = rsqrtf(tot / (float)DINNER + 1e-5f);
    }
    __syncthreads();
    float sc = sscale;
#pragma unroll
    for (int i = 0; i < 6; ++i) {
        int j = t + 256 * i;
        ybf[(long)row * DINNER + j] = f2bf(g[i] * sc * normw[j]);
    }
}

extern "C" void kernel_launch(void* const* d_in, const int* in_sizes, int n_in,
                              void* d_out, int out_size, void* d_ws, size_t ws_size,
                              hipStream_t stream) {
    const float* u = (const float*)d_in[0];
    const float* W_in = (const float*)d_in[1];
    const float* conv_w = (const float*)d_in[2];
    const float* conv_b = (const float*)d_in[3];
    const float* dt_bias = (const float*)d_in[4];
    const float* A_log = (const float*)d_in[5];
    const float* Dp = (const float*)d_in[6];
    const float* norm_w = (const float*)d_in[7];
    const float* W_out = (const float*)d_in[8];
    float* out = (float*)d_out;

    char* ws = (char*)d_ws;
    size_t off = 0;
    auto alloc = [&](size_t bytes) {
        void* p = ws + off;
        off += (bytes + 255) & ~(size_t)255;
        return p;
    };
    ushort_t* zbf = (ushort_t*)alloc((size_t)BROWS * DINNER * 2);      // 25.2 MB
    float* xbcraw = (float*)alloc((size_t)BROWS * XBCW * 4);           // 54.5 MB
    float* xbc = (float*)alloc((size_t)BROWS * XBCW * 4);              // 54.5 MB
    float* dtbT = (float*)alloc((size_t)NH * BROWS * 4);               // 0.79 MB
    float* acs = (float*)alloc((size_t)2 * NH * NCHUNK * 64 * 4);      // 0.79 MB
    float* Tsum = (float*)alloc((size_t)2 * NH * NCHUNK * 4);          // 12 KB
    ushort_t* states = (ushort_t*)alloc((size_t)2 * NH * NCHUNK * 4096 * 2);  // 25.2 MB
    ushort_t* ybuf = (ushort_t*)alloc((size_t)BROWS * DINNER * 2);     // 25.2 MB
    ushort_t* ybf = (ushort_t*)xbcraw;  // alias: xbcraw dead after conv

    if (off > ws_size) {
        fill_kernel<<<(out_size + 255) / 256, 256, 0, stream>>>(out, out_size, 12345.0f);
        return;
    }

    // in-projection with split epilogue (z bf16 / xBC f32 / dt softplus transposed)
    gemm_bt<1><<<dim3(26, 64), 256, 0, stream>>>(u, W_in, nullptr, DM, 0, DINPROJ,
                                                 zbf, xbcraw, dtbT, dt_bias);

    conv_kernel<<<dim3(BROWS, 7), 256, 0, stream>>>(xbcraw, conv_w, conv_b, xbc);

    acs_kernel<<<2 * NH, 256, 0, stream>>>(dtbT, A_log, acs, Tsum);
    states_kernel<<<dim3(NH, NCHUNK, 2), 256, 0, stream>>>(xbc, dtbT, acs, Tsum, states);
    scan_kernel<<<dim3(16, NH, 2), 256, 0, stream>>>(Tsum, states);
    yfull_kernel<<<dim3(NH, NCHUNK, 2), 256, 0, stream>>>(xbc, dtbT, acs, states, ybuf);

    norm_kernel<<<BROWS, 256, 0, stream>>>(ybuf, xbc, zbf, Dp, norm_w, ybf);

    // out-projection
    gemm_bt<0><<<dim3(6, 64), 256, 0, stream>>>(ybf, W_out, out, DINNER, DM, DM,
                                                nullptr, nullptr, nullptr, nullptr);
}

// Round 8
// 701.856 us; speedup vs baseline: 2.8059x; 2.8059x over previous
//
#include <hip/hip_runtime.h>

typedef __attribute__((ext_vector_type(4))) float f4;
typedef __attribute__((ext_vector_type(8))) short bfx8;
typedef __attribute__((ext_vector_type(4))) float f32x4;
typedef __attribute__((ext_vector_type(4))) unsigned int u32x4;
typedef __attribute__((ext_vector_type(4))) unsigned short u16x4;
typedef unsigned short ushort_t;

#define DM 768
#define DINNER 1536
#define NH 24
#define XBCW 1664
#define DINPROJ 3224
#define NCHUNK 64
#define BROWS 8192
#define PAD 68  // LDS row stride (floats) for 64-wide tiles

__device__ inline ushort_t f2bf(float f) {
    unsigned u = __builtin_bit_cast(unsigned, f);
    unsigned r = (u + 0x7FFF + ((u >> 16) & 1)) >> 16;
    return (ushort_t)r;
}
__device__ inline float bf2f(ushort_t u) {
    return __builtin_bit_cast(float, (unsigned)u << 16);
}
__device__ inline u32x4 pack8(f4 a, f4 b) {
    u32x4 o;
    o[0] = (unsigned)f2bf(a[0]) | ((unsigned)f2bf(a[1]) << 16);
    o[1] = (unsigned)f2bf(a[2]) | ((unsigned)f2bf(a[3]) << 16);
    o[2] = (unsigned)f2bf(b[0]) | ((unsigned)f2bf(b[1]) << 16);
    o[3] = (unsigned)f2bf(b[2]) | ((unsigned)f2bf(b[3]) << 16);
    return o;
}

__global__ __launch_bounds__(256) void fill_kernel(float* out, int n, float v) {
    int i = blockIdx.x * 256 + threadIdx.x;
    if (i < n) out[i] = v;
}

// ---- GEMM C = A[M][K] * B[N][K]^T (B f32, staged to bf16).
// EPI=0: A bf16, C f32 dense (out-proj). EPI=1: A f32 (u), split epilogue (in-proj).
template <int EPI>
__global__ __launch_bounds__(256) void gemm_bt(const void* __restrict__ Ap,
                                               const float* __restrict__ B,
                                               float* __restrict__ C,
                                               int K, int ldc, int nrowsB,
                                               ushort_t* __restrict__ zbf,
                                               float* __restrict__ xbcraw,
                                               float* __restrict__ dtbT,
                                               const float* __restrict__ dt_bias) {
    __shared__ __align__(16) ushort_t As[128 * 32];
    __shared__ __align__(16) ushort_t Bs[128 * 32];
    int tid = threadIdx.x;
    int lane = tid & 63;
    int w = tid >> 6;
    int wr = w >> 1, wc = w & 1;
    int m0 = blockIdx.y * 128;
    int n0 = blockIdx.x * 128;
    int r16 = lane & 15, kg = lane >> 4;

    f32x4 acc[4][4] = {};

    for (int k0 = 0; k0 < K; k0 += 32) {
        u32x4 av[2], bv[2];
#pragma unroll
        for (int r = 0; r < 2; ++r) {
            int chunk = tid + 256 * r;
            int row = chunk >> 2, cof = (chunk & 3) * 8;
            if (EPI == 1) {
                const float* A = (const float*)Ap;
                f4 a0 = *(const f4*)&A[(long)(m0 + row) * K + k0 + cof];
                f4 a1 = *(const f4*)&A[(long)(m0 + row) * K + k0 + cof + 4];
                av[r] = pack8(a0, a1);
            } else {
                const ushort_t* A = (const ushort_t*)Ap;
                av[r] = *(const u32x4*)&A[(long)(m0 + row) * K + k0 + cof];
            }
            int br = n0 + row;
            if (br < nrowsB) {
                f4 b0 = *(const f4*)&B[(long)br * K + k0 + cof];
                f4 b1 = *(const f4*)&B[(long)br * K + k0 + cof + 4];
                bv[r] = pack8(b0, b1);
            } else {
                bv[r] = (u32x4){0, 0, 0, 0};
            }
        }
        __syncthreads();
#pragma unroll
        for (int r = 0; r < 2; ++r) {
            int chunk = tid + 256 * r;
            int row = chunk >> 2, cof = (chunk & 3) * 8;
            *(u32x4*)&As[row * 32 + cof] = av[r];
            *(u32x4*)&Bs[row * 32 + cof] = bv[r];
        }
        __syncthreads();
        bfx8 af[4], bfr[4];
#pragma unroll
        for (int i = 0; i < 4; ++i) {
            af[i] = *(const bfx8*)&As[(wr * 64 + i * 16 + r16) * 32 + kg * 8];
            bfr[i] = *(const bfx8*)&Bs[(wc * 64 + i * 16 + r16) * 32 + kg * 8];
        }
#pragma unroll
        for (int i = 0; i < 4; ++i)
#pragma unroll
            for (int j = 0; j < 4; ++j)
                acc[i][j] = __builtin_amdgcn_mfma_f32_16x16x32_bf16(af[i], bfr[j], acc[i][j], 0, 0, 0);
    }

#pragma unroll
    for (int i = 0; i < 4; ++i) {
        int rowb = m0 + wr * 64 + i * 16 + kg * 4;
#pragma unroll
        for (int j = 0; j < 4; ++j) {
            int col = n0 + wc * 64 + j * 16 + r16;
            if (EPI == 0) {
#pragma unroll
                for (int q = 0; q < 4; ++q)
                    C[(long)(rowb + q) * ldc + col] = acc[i][j][q];
            } else {
                if (n0 < DINNER) {  // z -> bf16
#pragma unroll
                    for (int q = 0; q < 4; ++q)
                        zbf[(long)(rowb + q) * DINNER + col] = f2bf(acc[i][j][q]);
                } else if (n0 < 3200) {  // xBC raw -> f32
#pragma unroll
                    for (int q = 0; q < 4; ++q)
                        xbcraw[(long)(rowb + q) * XBCW + col - DINNER] = acc[i][j][q];
                } else if (col < DINPROJ) {  // dt -> softplus -> transposed
                    int h = col - 3200;
                    float bias = dt_bias[h];
#pragma unroll
                    for (int q = 0; q < 4; ++q) {
                        float v = acc[i][j][q] + bias;
                        float d = (v > 20.f) ? v : log1pf(__expf(v));
                        dtbT[(long)h * BROWS + rowb + q] = d;
                    }
                }
            }
        }
    }
}

// ---- depthwise causal conv(4) + bias + silu (dense in/out) ----
__global__ __launch_bounds__(256) void conv_kernel(const float* __restrict__ xin,
                                                   const float* __restrict__ cw,
                                                   const float* __restrict__ cb,
                                                   float* __restrict__ xbc) {
    int ch = blockIdx.y * 256 + threadIdx.x;
    int row = blockIdx.x;
    if (ch >= XBCW) return;
    int b = row >> 12;
    int l = row & 4095;
    float acc = cb[ch];
#pragma unroll
    for (int k = 0; k < 4; ++k) {
        int ll = l - 3 + k;
        if (ll >= 0)
            acc += cw[ch * 4 + k] * xin[(long)(b * 4096 + ll) * XBCW + ch];
    }
    float s = acc / (1.f + __expf(-acc));
    xbc[(long)row * XBCW + ch] = s;
}

// ---- per-chunk cumsum of A*dt via wave scan ----
__global__ __launch_bounds__(256) void acs_kernel(const float* __restrict__ dtbT,
                                                  const float* __restrict__ A_log,
                                                  float* __restrict__ acs,
                                                  float* __restrict__ Tsum) {
    int bh = blockIdx.x;  // b*24+h
    int b = bh / NH, h = bh % NH;
    int t = threadIdx.x;
    int lane = t & 63;
    float A = -__expf(A_log[h]);
    const float* dp = &dtbT[(long)h * BROWS + b * 4096];
#pragma unroll
    for (int it = 0; it < 16; ++it) {
        int c = (t >> 6) + 4 * it;
        float v = A * dp[c * 64 + lane];
#pragma unroll
        for (int off = 1; off < 64; off <<= 1) {
            float u = __shfl_up(v, off, 64);
            if (lane >= off) v += u;
        }
        acs[((long)bh * NCHUNK + c) * 64 + lane] = v;
        if (lane == 63) Tsum[bh * NCHUNK + c] = v;
    }
}

// ---- phase A: per-chunk states[p][n] -> bf16 ----
__global__ __launch_bounds__(256) void states_kernel(const float* __restrict__ xbc,
                                                     const float* __restrict__ dtbT,
                                                     const float* __restrict__ acs,
                                                     const float* __restrict__ Tsum,
                                                     ushort_t* __restrict__ states) {
    int h = blockIdx.x, c = blockIdx.y, b = blockIdx.z;
    __shared__ __align__(16) float sW[64 * PAD];
    __shared__ __align__(16) float sB[64 * PAD];
    __shared__ float sWt[64];
    int t = threadIdx.x;
    long rowg0 = (long)b * 4096 + c * 64;
    long acsb = ((long)(b * NH + h) * NCHUNK + c) * 64;
    float T = Tsum[(b * NH + h) * NCHUNK + c];
    if (t < 64)
        sWt[t] = dtbT[(long)h * BROWS + rowg0 + t] * __expf(T - acs[acsb + t]);
    __syncthreads();
#pragma unroll
    for (int i = 0; i < 4; ++i) {
        int q = t + 256 * i;
        int l = q >> 4, m = q & 15;
        const float* rp = &xbc[(rowg0 + l) * (long)XBCW];
        f4 gx = *(const f4*)&rp[h * 64 + 4 * m];
        float wt = sWt[l];
        gx[0] *= wt; gx[1] *= wt; gx[2] *= wt; gx[3] *= wt;
        *(f4*)&sW[l * PAD + 4 * m] = gx;
        f4 gb = *(const f4*)&rp[DINNER + 4 * m];
        *(f4*)&sB[l * PAD + 4 * m] = gb;
    }
    __syncthreads();
    int p0 = (t >> 4) * 4, n0 = (t & 15) * 4;
    float acc[4][4] = {};
    for (int l4 = 0; l4 < 16; ++l4) {
#pragma unroll
        for (int qq = 0; qq < 4; ++qq) {
            int l = 4 * l4 + qq;
            f4 wv = *(const f4*)&sW[l * PAD + p0];
            f4 bv = *(const f4*)&sB[l * PAD + n0];
#pragma unroll
            for (int i = 0; i < 4; ++i)
#pragma unroll
                for (int j = 0; j < 4; ++j)
                    acc[i][j] += wv[i] * bv[j];
        }
    }
    long ob = ((long)(b * NH + h) * NCHUNK + c) * 4096;
#pragma unroll
    for (int i = 0; i < 4; ++i) {
        u16x4 o;
#pragma unroll
        for (int j = 0; j < 4; ++j) o[j] = f2bf(acc[i][j]);
        *(u16x4*)&states[ob + (p0 + i) * 64 + n0] = o;
    }
}

// ---- sequential chunk scan ----
__global__ __launch_bounds__(256) void scan_kernel(const float* __restrict__ Tsum,
                                                   ushort_t* __restrict__ states) {
    int e = blockIdx.x * 256 + threadIdx.x;
    int h = blockIdx.y, b = blockIdx.z;
    long base = ((long)(b * NH + h)) * NCHUNK * 4096 + e;
    const float* Tp = &Tsum[(b * NH + h) * NCHUNK];
    float acc = 0.f;
    for (int c = 0; c < NCHUNK; ++c) {
        float cur = bf2f(states[base + (long)c * 4096]);
        states[base + (long)c * 4096] = f2bf(acc);
        acc = __expf(Tp[c]) * acc + cur;
    }
}

// ---- phase C: Y -> dense bf16 ybuf ----
__global__ __launch_bounds__(256) void yfull_kernel(const float* __restrict__ xbc,
                                                    const float* __restrict__ dtbT,
                                                    const float* __restrict__ acs,
                                                    const ushort_t* __restrict__ sprev,
                                                    ushort_t* __restrict__ ybuf) {
    int h = blockIdx.x, c = blockIdx.y, b = blockIdx.z;
    __shared__ __align__(16) float bufC[64 * PAD];  // C[l][n]
    __shared__ __align__(16) float bufX[64 * PAD];  // BT[n][s] -> xd[s][p] -> sprevT[n][p]
    __shared__ __align__(16) float bufS[64 * PAD];  // scores[l][s]
    __shared__ float sAcs[64], sE[64], sDt[64];
    int t = threadIdx.x;
    long rowg0 = (long)b * 4096 + c * 64;
    long acsb = ((long)(b * NH + h) * NCHUNK + c) * 64;
    if (t < 64) {
        float a = acs[acsb + t];
        sAcs[t] = a;
        sE[t] = __expf(a);
        sDt[t] = dtbT[(long)h * BROWS + rowg0 + t];
    }
    // stage C dense, B transposed
#pragma unroll
    for (int i = 0; i < 4; ++i) {
        int q = t + 256 * i;
        int l = q >> 4, m = q & 15;
        const float* rp = &xbc[(rowg0 + l) * (long)XBCW];
        f4 gC = *(const f4*)&rp[1600 + 4 * m];
        *(f4*)&bufC[l * PAD + 4 * m] = gC;
        f4 gB = *(const f4*)&rp[DINNER + 4 * m];
        bufX[(4 * m + 0) * PAD + l] = gB[0];
        bufX[(4 * m + 1) * PAD + l] = gB[1];
        bufX[(4 * m + 2) * PAD + l] = gB[2];
        bufX[(4 * m + 3) * PAD + l] = gB[3];
    }
    __syncthreads();
    int l0 = (t >> 4) * 4, s0 = (t & 15) * 4;
    // phase 1: sc = C.B^T
    float acc[4][4] = {};
    for (int n4 = 0; n4 < 16; ++n4) {
        f4 cv[4];
#pragma unroll
        for (int i = 0; i < 4; ++i) cv[i] = *(const f4*)&bufC[(l0 + i) * PAD + 4 * n4];
#pragma unroll
        for (int qq = 0; qq < 4; ++qq) {
            f4 bq = *(const f4*)&bufX[(4 * n4 + qq) * PAD + s0];
#pragma unroll
            for (int i = 0; i < 4; ++i)
#pragma unroll
                for (int j = 0; j < 4; ++j)
                    acc[i][j] += cv[i][qq] * bq[j];
        }
    }
    __syncthreads();  // all BT reads done
    // mask+decay -> bufS; stage xd into bufX
#pragma unroll
    for (int i = 0; i < 4; ++i) {
        int l = l0 + i;
        f4 o;
#pragma unroll
        for (int j = 0; j < 4; ++j) {
            int s = s0 + j;
            o[j] = (s <= l) ? acc[i][j] * __expf(sAcs[l] - sAcs[s]) : 0.f;
        }
        *(f4*)&bufS[l * PAD + s0] = o;
    }
#pragma unroll
    for (int i = 0; i < 4; ++i) {
        int q = t + 256 * i;
        int l = q >> 4, m = q & 15;
        f4 gx = *(const f4*)&xbc[(rowg0 + l) * (long)XBCW + h * 64 + 4 * m];
        float d = sDt[l];
        gx[0] *= d; gx[1] *= d; gx[2] *= d; gx[3] *= d;
        *(f4*)&bufX[l * PAD + 4 * m] = gx;
    }
    __syncthreads();
    // phase 2: yd = S.xd
    float yd[4][4] = {};
    for (int s4 = 0; s4 < 16; ++s4) {
        f4 sv[4];
#pragma unroll
        for (int i = 0; i < 4; ++i) sv[i] = *(const f4*)&bufS[(l0 + i) * PAD + 4 * s4];
#pragma unroll
        for (int qq = 0; qq < 4; ++qq) {
            f4 xq = *(const f4*)&bufX[(4 * s4 + qq) * PAD + s0];
#pragma unroll
            for (int i = 0; i < 4; ++i)
#pragma unroll
                for (int j = 0; j < 4; ++j)
                    yd[i][j] += sv[i][qq] * xq[j];
        }
    }
    __syncthreads();  // xd reads done
    // stage sprev transposed
    long spb = ((long)(b * NH + h) * NCHUNK + c) * 4096;
#pragma unroll
    for (int i = 0; i < 4; ++i) {
        int q = t + 256 * i;
        int p = q >> 4, m = q & 15;
        u16x4 gs = *(const u16x4*)&sprev[spb + p * 64 + 4 * m];
        bufX[(4 * m + 0) * PAD + p] = bf2f(gs[0]);
        bufX[(4 * m + 1) * PAD + p] = bf2f(gs[1]);
        bufX[(4 * m + 2) * PAD + p] = bf2f(gs[2]);
        bufX[(4 * m + 3) * PAD + p] = bf2f(gs[3]);
    }
    __syncthreads();
    // phase 3: yo = C.Sprev^T
    float yo[4][4] = {};
    for (int n4 = 0; n4 < 16; ++n4) {
        f4 cv[4];
#pragma unroll
        for (int i = 0; i < 4; ++i) cv[i] = *(const f4*)&bufC[(l0 + i) * PAD + 4 * n4];
#pragma unroll
        for (int qq = 0; qq < 4; ++qq) {
            f4 pq = *(const f4*)&bufX[(4 * n4 + qq) * PAD + s0];
#pragma unroll
            for (int i = 0; i < 4; ++i)
#pragma unroll
                for (int j = 0; j < 4; ++j)
                    yo[i][j] += cv[i][qq] * pq[j];
        }
    }
    // epilogue: dense bf16
#pragma unroll
    for (int i = 0; i < 4; ++i) {
        int l = l0 + i;
        u16x4 o;
#pragma unroll
        for (int j = 0; j < 4; ++j) o[j] = f2bf(yd[i][j] + sE[l] * yo[i][j]);
        *(u16x4*)&ybuf[(rowg0 + l) * (long)DINNER + h * 64 + s0] = o;
    }
}

// ---- gated RMS norm -> bf16 ----
__global__ __launch_bounds__(256) void norm_kernel(const ushort_t* __restrict__ ybuf,
                                                   const float* __restrict__ xbc,
                                                   const ushort_t* __restrict__ zbf,
                                                   const float* __restrict__ Dp,
                                                   const float* __restrict__ normw,
                                                   ushort_t* __restrict__ ybf) {
    int row = blockIdx.x;
    int t = threadIdx.x;
    float g[6];
    float ss = 0.f;
#pragma unroll
    for (int i = 0; i < 6; ++i) {
        int j = t + 256 * i;
        int h = j >> 6;
        float x = xbc[(long)row * XBCW + j];
        float yy = bf2f(ybuf[(long)row * DINNER + j]) + x * Dp[h];
        float z = bf2f(zbf[(long)row * DINNER + j]);
        float gz = z / (1.f + __expf(-z));
        float v = yy * gz;
        g[i] = v;
        ss += v * v;
    }
#pragma unroll
    for (int o = 32; o > 0; o >>= 1) ss += __shfl_xor(ss, o, 64);
    __shared__ float wsum[4];
    __shared__ float sscale;
    int w = t >> 6;
    if ((t & 63) == 0) wsum[w] = ss;
    __syncthreads();
    if (t == 0) {
        float tot = wsum[0] + wsum[1] + wsum[2] + wsum[3];
        sscale = rsqrtf(tot / (float)DINNER + 1e-5f);
    }
    __syncthreads();
    float sc = sscale;
#pragma unroll
    for (int i = 0; i < 6; ++i) {
        int j = t + 256 * i;
        ybf[(long)row * DINNER + j] = f2bf(g[i] * sc * normw[j]);
    }
}

extern "C" void kernel_launch(void* const* d_in, const int* in_sizes, int n_in,
                              void* d_out, int out_size, void* d_ws, size_t ws_size,
                              hipStream_t stream) {
    const float* u = (const float*)d_in[0];
    const float* W_in = (const float*)d_in[1];
    const float* conv_w = (const float*)d_in[2];
    const float* conv_b = (const float*)d_in[3];
    const float* dt_bias = (const float*)d_in[4];
    const float* A_log = (const float*)d_in[5];
    const float* Dp = (const float*)d_in[6];
    const float* norm_w = (const float*)d_in[7];
    const float* W_out = (const float*)d_in[8];
    float* out = (float*)d_out;

    char* ws = (char*)d_ws;
    size_t off = 0;
    auto alloc = [&](size_t bytes) {
        void* p = ws + off;
        off += (bytes + 255) & ~(size_t)255;
        return p;
    };
    ushort_t* zbf = (ushort_t*)alloc((size_t)BROWS * DINNER * 2);      // 25.2 MB
    float* xbcraw = (float*)alloc((size_t)BROWS * XBCW * 4);           // 54.5 MB
    float* xbc = (float*)alloc((size_t)BROWS * XBCW * 4);              // 54.5 MB
    float* dtbT = (float*)alloc((size_t)NH * BROWS * 4);               // 0.79 MB
    float* acs = (float*)alloc((size_t)2 * NH * NCHUNK * 64 * 4);      // 0.79 MB
    float* Tsum = (float*)alloc((size_t)2 * NH * NCHUNK * 4);          // 12 KB
    ushort_t* states = (ushort_t*)alloc((size_t)2 * NH * NCHUNK * 4096 * 2);  // 25.2 MB
    ushort_t* ybuf = (ushort_t*)alloc((size_t)BROWS * DINNER * 2);     // 25.2 MB
    ushort_t* ybf = (ushort_t*)xbcraw;  // alias: xbcraw dead after conv

    if (off > ws_size) {
        fill_kernel<<<(out_size + 255) / 256, 256, 0, stream>>>(out, out_size, 12345.0f);
        return;
    }

    // in-projection with split epilogue (z bf16 / xBC f32 / dt softplus transposed)
    gemm_bt<1><<<dim3(26, 64), 256, 0, stream>>>(u, W_in, nullptr, DM, 0, DINPROJ,
                                                 zbf, xbcraw, dtbT, dt_bias);

    conv_kernel<<<dim3(BROWS, 7), 256, 0, stream>>>(xbcraw, conv_w, conv_b, xbc);

    acs_kernel<<<2 * NH, 256, 0, stream>>>(dtbT, A_log, acs, Tsum);
    states_kernel<<<dim3(NH, NCHUNK, 2), 256, 0, stream>>>(xbc, dtbT, acs, Tsum, states);
    scan_kernel<<<dim3(16, NH, 2), 256, 0, stream>>>(Tsum, states);
    yfull_kernel<<<dim3(NH, NCHUNK, 2), 256, 0, stream>>>(xbc, dtbT, acs, states, ybuf);

    norm_kernel<<<BROWS, 256, 0, stream>>>(ybuf, xbc, zbf, Dp, norm_w, ybf);

    // out-projection
    gemm_bt<0><<<dim3(6, 64), 256, 0, stream>>>(ybf, W_out, out, DINNER, DM, DM,
                                                nullptr, nullptr, nullptr, nullptr);
}

// Round 9
// 335.620 us; speedup vs baseline: 5.8677x; 2.0912x over previous
//
#include <hip/hip_runtime.h>

typedef __attribute__((ext_vector_type(4))) float f4;
typedef __attribute__((ext_vector_type(8))) short bfx8;
typedef __attribute__((ext_vector_type(4))) float f32x4;
typedef __attribute__((ext_vector_type(4))) unsigned int u32x4;
typedef __attribute__((ext_vector_type(4))) unsigned short u16x4;
typedef __attribute__((ext_vector_type(8))) unsigned short u16x8;
typedef unsigned short ushort_t;

#define DM 768
#define DINNER 1536
#define NH 24
#define XBCW 1664
#define DINPROJ 3224
#define NCHUNK 64
#define BROWS 8192
#define PADB 72  // bf16 LDS row stride for 64-wide tiles (144 B: 16B-aligned, 2-way bank alias)

__device__ inline ushort_t f2bf(float f) {
    unsigned u = __builtin_bit_cast(unsigned, f);
    unsigned r = (u + 0x7FFF + ((u >> 16) & 1)) >> 16;
    return (ushort_t)r;
}
__device__ inline float bf2f(ushort_t u) {
    return __builtin_bit_cast(float, (unsigned)u << 16);
}
__device__ inline u32x4 pack8(f4 a, f4 b) {
    u32x4 o;
    o[0] = (unsigned)f2bf(a[0]) | ((unsigned)f2bf(a[1]) << 16);
    o[1] = (unsigned)f2bf(a[2]) | ((unsigned)f2bf(a[3]) << 16);
    o[2] = (unsigned)f2bf(b[0]) | ((unsigned)f2bf(b[1]) << 16);
    o[3] = (unsigned)f2bf(b[2]) | ((unsigned)f2bf(b[3]) << 16);
    return o;
}

__global__ __launch_bounds__(256) void fill_kernel(float* out, int n, float v) {
    int i = blockIdx.x * 256 + threadIdx.x;
    if (i < n) out[i] = v;
}

// ---- GEMM C = A[M][K] * B[N][K]^T (B f32, staged to bf16).
// EPI=0: A bf16, C f32 dense (out-proj). EPI=1: A f32 (u), split epilogue (in-proj).
template <int EPI>
__global__ __launch_bounds__(256) void gemm_bt(const void* __restrict__ Ap,
                                               const float* __restrict__ B,
                                               float* __restrict__ C,
                                               int K, int ldc, int nrowsB,
                                               ushort_t* __restrict__ zbf,
                                               float* __restrict__ xbcraw,
                                               float* __restrict__ dtbT,
                                               const float* __restrict__ dt_bias) {
    __shared__ __align__(16) ushort_t As[128 * 32];
    __shared__ __align__(16) ushort_t Bs[128 * 32];
    int tid = threadIdx.x;
    int lane = tid & 63;
    int w = tid >> 6;
    int wr = w >> 1, wc = w & 1;
    int m0 = blockIdx.y * 128;
    int n0 = blockIdx.x * 128;
    int r16 = lane & 15, kg = lane >> 4;

    f32x4 acc[4][4] = {};

    for (int k0 = 0; k0 < K; k0 += 32) {
        u32x4 av[2], bv[2];
#pragma unroll
        for (int r = 0; r < 2; ++r) {
            int chunk = tid + 256 * r;
            int row = chunk >> 2, cof = (chunk & 3) * 8;
            if (EPI == 1) {
                const float* A = (const float*)Ap;
                f4 a0 = *(const f4*)&A[(long)(m0 + row) * K + k0 + cof];
                f4 a1 = *(const f4*)&A[(long)(m0 + row) * K + k0 + cof + 4];
                av[r] = pack8(a0, a1);
            } else {
                const ushort_t* A = (const ushort_t*)Ap;
                av[r] = *(const u32x4*)&A[(long)(m0 + row) * K + k0 + cof];
            }
            int br = n0 + row;
            if (br < nrowsB) {
                f4 b0 = *(const f4*)&B[(long)br * K + k0 + cof];
                f4 b1 = *(const f4*)&B[(long)br * K + k0 + cof + 4];
                bv[r] = pack8(b0, b1);
            } else {
                bv[r] = (u32x4){0, 0, 0, 0};
            }
        }
        __syncthreads();
#pragma unroll
        for (int r = 0; r < 2; ++r) {
            int chunk = tid + 256 * r;
            int row = chunk >> 2, cof = (chunk & 3) * 8;
            *(u32x4*)&As[row * 32 + cof] = av[r];
            *(u32x4*)&Bs[row * 32 + cof] = bv[r];
        }
        __syncthreads();
        bfx8 af[4], bfr[4];
#pragma unroll
        for (int i = 0; i < 4; ++i) {
            af[i] = *(const bfx8*)&As[(wr * 64 + i * 16 + r16) * 32 + kg * 8];
            bfr[i] = *(const bfx8*)&Bs[(wc * 64 + i * 16 + r16) * 32 + kg * 8];
        }
#pragma unroll
        for (int i = 0; i < 4; ++i)
#pragma unroll
            for (int j = 0; j < 4; ++j)
                acc[i][j] = __builtin_amdgcn_mfma_f32_16x16x32_bf16(af[i], bfr[j], acc[i][j], 0, 0, 0);
    }

#pragma unroll
    for (int i = 0; i < 4; ++i) {
        int rowb = m0 + wr * 64 + i * 16 + kg * 4;
#pragma unroll
        for (int j = 0; j < 4; ++j) {
            int col = n0 + wc * 64 + j * 16 + r16;
            if (EPI == 0) {
#pragma unroll
                for (int q = 0; q < 4; ++q)
                    C[(long)(rowb + q) * ldc + col] = acc[i][j][q];
            } else {
                if (n0 < DINNER) {  // z -> bf16
#pragma unroll
                    for (int q = 0; q < 4; ++q)
                        zbf[(long)(rowb + q) * DINNER + col] = f2bf(acc[i][j][q]);
                } else if (n0 < 3200) {  // xBC raw -> f32
#pragma unroll
                    for (int q = 0; q < 4; ++q)
                        xbcraw[(long)(rowb + q) * XBCW + col - DINNER] = acc[i][j][q];
                } else if (col < DINPROJ) {  // dt -> softplus -> transposed
                    int h = col - 3200;
                    float bias = dt_bias[h];
#pragma unroll
                    for (int q = 0; q < 4; ++q) {
                        float v = acc[i][j][q] + bias;
                        float d = (v > 20.f) ? v : log1pf(__expf(v));
                        dtbT[(long)h * BROWS + rowb + q] = d;
                    }
                }
            }
        }
    }
}

// ---- depthwise causal conv(4) + bias + silu (dense in/out) ----
__global__ __launch_bounds__(256) void conv_kernel(const float* __restrict__ xin,
                                                   const float* __restrict__ cw,
                                                   const float* __restrict__ cb,
                                                   float* __restrict__ xbc) {
    int ch = blockIdx.y * 256 + threadIdx.x;
    int row = blockIdx.x;
    if (ch >= XBCW) return;
    int b = row >> 12;
    int l = row & 4095;
    float acc = cb[ch];
#pragma unroll
    for (int k = 0; k < 4; ++k) {
        int ll = l - 3 + k;
        if (ll >= 0)
            acc += cw[ch * 4 + k] * xin[(long)(b * 4096 + ll) * XBCW + ch];
    }
    float s = acc / (1.f + __expf(-acc));
    xbc[(long)row * XBCW + ch] = s;
}

// ---- per-chunk cumsum of A*dt via wave scan ----
__global__ __launch_bounds__(256) void acs_kernel(const float* __restrict__ dtbT,
                                                  const float* __restrict__ A_log,
                                                  float* __restrict__ acs,
                                                  float* __restrict__ Tsum) {
    int bh = blockIdx.x;  // b*24+h
    int b = bh / NH, h = bh % NH;
    int t = threadIdx.x;
    int lane = t & 63;
    float A = -__expf(A_log[h]);
    const float* dp = &dtbT[(long)h * BROWS + b * 4096];
#pragma unroll
    for (int it = 0; it < 16; ++it) {
        int c = (t >> 6) + 4 * it;
        float v = A * dp[c * 64 + lane];
#pragma unroll
        for (int off = 1; off < 64; off <<= 1) {
            float u = __shfl_up(v, off, 64);
            if (lane >= off) v += u;
        }
        acs[((long)bh * NCHUNK + c) * 64 + lane] = v;
        if (lane == 63) Tsum[bh * NCHUNK + c] = v;
    }
}

// ---- phase A (MFMA): states[p][n] = sum_l (x*dt*decay)[l][p] * B[l][n] -> bf16 ----
__global__ __launch_bounds__(256) void states_kernel(const float* __restrict__ xbc,
                                                     const float* __restrict__ dtbT,
                                                     const float* __restrict__ acs,
                                                     const float* __restrict__ Tsum,
                                                     ushort_t* __restrict__ states) {
    int h = blockIdx.x, c = blockIdx.y, b = blockIdx.z;
    __shared__ __align__(16) ushort_t Wt[64 * PADB];  // wT[p][l], then output tile [p][n]
    __shared__ __align__(16) ushort_t Bt[64 * PADB];  // BT[n][l]
    int t = threadIdx.x;
    long rowg0 = (long)b * 4096 + c * 64;
    long acsb = ((long)(b * NH + h) * NCHUNK + c) * 64;
    float T = Tsum[(b * NH + h) * NCHUNK + c];
#pragma unroll
    for (int i = 0; i < 2; ++i) {
        int q = t + 256 * i;
        int l = q >> 3, sg = q & 7;
        const float* rp = &xbc[(rowg0 + l) * (long)XBCW];
        float dec = dtbT[(long)h * BROWS + rowg0 + l] * __expf(T - acs[acsb + l]);
        f4 x0 = *(const f4*)&rp[h * 64 + sg * 8];
        f4 x1 = *(const f4*)&rp[h * 64 + sg * 8 + 4];
        f4 b0 = *(const f4*)&rp[DINNER + sg * 8];
        f4 b1 = *(const f4*)&rp[DINNER + sg * 8 + 4];
#pragma unroll
        for (int jj = 0; jj < 4; ++jj) {
            Wt[(sg * 8 + jj) * PADB + l] = f2bf(x0[jj] * dec);
            Wt[(sg * 8 + 4 + jj) * PADB + l] = f2bf(x1[jj] * dec);
            Bt[(sg * 8 + jj) * PADB + l] = f2bf(b0[jj]);
            Bt[(sg * 8 + 4 + jj) * PADB + l] = f2bf(b1[jj]);
        }
    }
    __syncthreads();
    int w = t >> 6, lane = t & 63;
    int r16 = lane & 15, kg = lane >> 4;
    bfx8 aw[2];
#pragma unroll
    for (int kk = 0; kk < 2; ++kk)
        aw[kk] = *(const bfx8*)&Wt[(w * 16 + r16) * PADB + kk * 32 + kg * 8];
    f32x4 acc[4] = {};
#pragma unroll
    for (int j = 0; j < 4; ++j)
#pragma unroll
        for (int kk = 0; kk < 2; ++kk) {
            bfx8 bb = *(const bfx8*)&Bt[(j * 16 + r16) * PADB + kk * 32 + kg * 8];
            acc[j] = __builtin_amdgcn_mfma_f32_16x16x32_bf16(aw[kk], bb, acc[j], 0, 0, 0);
        }
    __syncthreads();
#pragma unroll
    for (int j = 0; j < 4; ++j)
#pragma unroll
        for (int q = 0; q < 4; ++q)
            Wt[(w * 16 + kg * 4 + q) * PADB + j * 16 + r16] = f2bf(acc[j][q]);
    __syncthreads();
    long ob = ((long)(b * NH + h) * NCHUNK + c) * 4096;
#pragma unroll
    for (int i = 0; i < 2; ++i) {
        int q = t + 256 * i;
        int p = q >> 3, sg = q & 7;
        *(u16x8*)&states[ob + p * 64 + sg * 8] = *(const u16x8*)&Wt[p * PADB + sg * 8];
    }
}

// ---- sequential chunk scan ----
__global__ __launch_bounds__(256) void scan_kernel(const float* __restrict__ Tsum,
                                                   ushort_t* __restrict__ states) {
    int e = blockIdx.x * 256 + threadIdx.x;
    int h = blockIdx.y, b = blockIdx.z;
    long base = ((long)(b * NH + h)) * NCHUNK * 4096 + e;
    const float* Tp = &Tsum[(b * NH + h) * NCHUNK];
    float acc = 0.f;
    for (int c = 0; c < NCHUNK; ++c) {
        float cur = bf2f(states[base + (long)c * 4096]);
        states[base + (long)c * 4096] = f2bf(acc);
        acc = __expf(Tp[c]) * acc + cur;
    }
}

// ---- phase C (MFMA): Y = (C.B^T . Lm) @ xd + exp(acs) * (C @ Sprev^T) -> bf16 ybuf ----
__global__ __launch_bounds__(256) void yfull_kernel(const float* __restrict__ xbc,
                                                    const float* __restrict__ dtbT,
                                                    const float* __restrict__ acs,
                                                    const ushort_t* __restrict__ sprev,
                                                    ushort_t* __restrict__ ybuf) {
    int h = blockIdx.x, c = blockIdx.y, b = blockIdx.z;
    __shared__ __align__(16) ushort_t Cb[64 * PADB];  // C[l][n]
    __shared__ __align__(16) ushort_t Bb[64 * PADB];  // B[s][n], later output tile [l][p]
    __shared__ __align__(16) ushort_t Xt[64 * PADB];  // xd^T[p][s]
    __shared__ __align__(16) ushort_t Sp[64 * PADB];  // sprev[p][n]
    __shared__ __align__(16) ushort_t Sm[64 * PADB];  // masked scores [l][s]
    __shared__ float sAcs[64], sE[64];
    int t = threadIdx.x;
    long rowg0 = (long)b * 4096 + c * 64;
    long acsb = ((long)(b * NH + h) * NCHUNK + c) * 64;
    long spb = ((long)(b * NH + h) * NCHUNK + c) * 4096;
    if (t < 64) {
        float a = acs[acsb + t];
        sAcs[t] = a;
        sE[t] = __expf(a);
    }
#pragma unroll
    for (int i = 0; i < 2; ++i) {
        int q = t + 256 * i;
        int l = q >> 3, sg = q & 7;
        const float* rp = &xbc[(rowg0 + l) * (long)XBCW];
        f4 c0 = *(const f4*)&rp[1600 + sg * 8];
        f4 c1 = *(const f4*)&rp[1600 + sg * 8 + 4];
        *(u32x4*)&Cb[l * PADB + sg * 8] = pack8(c0, c1);
        f4 b0 = *(const f4*)&rp[DINNER + sg * 8];
        f4 b1 = *(const f4*)&rp[DINNER + sg * 8 + 4];
        *(u32x4*)&Bb[l * PADB + sg * 8] = pack8(b0, b1);
        float dtv = dtbT[(long)h * BROWS + rowg0 + l];
        f4 x0 = *(const f4*)&rp[h * 64 + sg * 8];
        f4 x1 = *(const f4*)&rp[h * 64 + sg * 8 + 4];
#pragma unroll
        for (int jj = 0; jj < 4; ++jj) {
            Xt[(sg * 8 + jj) * PADB + l] = f2bf(x0[jj] * dtv);
            Xt[(sg * 8 + 4 + jj) * PADB + l] = f2bf(x1[jj] * dtv);
        }
        *(u16x8*)&Sp[l * PADB + sg * 8] = *(const u16x8*)&sprev[spb + l * 64 + sg * 8];
    }
    __syncthreads();
    int w = t >> 6, lane = t & 63;
    int r16 = lane & 15, kg = lane >> 4;
    // phase 1: S = C.B^T (rows l in [16w,16w+16))
    bfx8 ac[2];
#pragma unroll
    for (int kk = 0; kk < 2; ++kk)
        ac[kk] = *(const bfx8*)&Cb[(w * 16 + r16) * PADB + kk * 32 + kg * 8];
    f32x4 s_acc[4] = {};
#pragma unroll
    for (int j = 0; j < 4; ++j)
#pragma unroll
        for (int kk = 0; kk < 2; ++kk) {
            bfx8 bb = *(const bfx8*)&Bb[(j * 16 + r16) * PADB + kk * 32 + kg * 8];
            s_acc[j] = __builtin_amdgcn_mfma_f32_16x16x32_bf16(ac[kk], bb, s_acc[j], 0, 0, 0);
        }
    // mask + decay -> Sm (bf16)
#pragma unroll
    for (int j = 0; j < 4; ++j)
#pragma unroll
        for (int q = 0; q < 4; ++q) {
            int l = w * 16 + kg * 4 + q;
            int s = j * 16 + r16;
            float v = s_acc[j][q];
            v = (s <= l) ? v * __expf(sAcs[l] - sAcs[s]) : 0.f;
            Sm[l * PADB + s] = f2bf(v);
        }
    __syncthreads();
    // phase 2: Yd = Sm @ xd (B-op = Xt[p][s]);  phase 3: Yo = C @ Sprev^T (B-op = Sp[p][n])
    bfx8 as[2];
#pragma unroll
    for (int kk = 0; kk < 2; ++kk)
        as[kk] = *(const bfx8*)&Sm[(w * 16 + r16) * PADB + kk * 32 + kg * 8];
    f32x4 d_acc[4] = {}, o_acc[4] = {};
#pragma unroll
    for (int j = 0; j < 4; ++j)
#pragma unroll
        for (int kk = 0; kk < 2; ++kk) {
            bfx8 xb = *(const bfx8*)&Xt[(j * 16 + r16) * PADB + kk * 32 + kg * 8];
            d_acc[j] = __builtin_amdgcn_mfma_f32_16x16x32_bf16(as[kk], xb, d_acc[j], 0, 0, 0);
            bfx8 sb = *(const bfx8*)&Sp[(j * 16 + r16) * PADB + kk * 32 + kg * 8];
            o_acc[j] = __builtin_amdgcn_mfma_f32_16x16x32_bf16(ac[kk], sb, o_acc[j], 0, 0, 0);
        }
    // epilogue tile -> Bb (dead), then coalesced copy out
#pragma unroll
    for (int j = 0; j < 4; ++j)
#pragma unroll
        for (int q = 0; q < 4; ++q) {
            int l = w * 16 + kg * 4 + q;
            int p = j * 16 + r16;
            Bb[l * PADB + p] = f2bf(d_acc[j][q] + sE[l] * o_acc[j][q]);
        }
    __syncthreads();
#pragma unroll
    for (int i = 0; i < 2; ++i) {
        int q = t + 256 * i;
        int l = q >> 3, sg = q & 7;
        *(u16x8*)&ybuf[(rowg0 + l) * (long)DINNER + h * 64 + sg * 8] =
            *(const u16x8*)&Bb[l * PADB + sg * 8];
    }
}

// ---- gated RMS norm -> bf16 ----
__global__ __launch_bounds__(256) void norm_kernel(const ushort_t* __restrict__ ybuf,
                                                   const float* __restrict__ xbc,
                                                   const ushort_t* __restrict__ zbf,
                                                   const float* __restrict__ Dp,
                                                   const float* __restrict__ normw,
                                                   ushort_t* __restrict__ ybf) {
    int row = blockIdx.x;
    int t = threadIdx.x;
    float g[6];
    float ss = 0.f;
#pragma unroll
    for (int i = 0; i < 6; ++i) {
        int j = t + 256 * i;
        int h = j >> 6;
        float x = xbc[(long)row * XBCW + j];
        float yy = bf2f(ybuf[(long)row * DINNER + j]) + x * Dp[h];
        float z = bf2f(zbf[(long)row * DINNER + j]);
        float gz = z / (1.f + __expf(-z));
        float v = yy * gz;
        g[i] = v;
        ss += v * v;
    }
#pragma unroll
    for (int o = 32; o > 0; o >>= 1) ss += __shfl_xor(ss, o, 64);
    __shared__ float wsum[4];
    __shared__ float sscale;
    int w = t >> 6;
    if ((t & 63) == 0) wsum[w] = ss;
    __syncthreads();
    if (t == 0) {
        float tot = wsum[0] + wsum[1] + wsum[2] + wsum[3];
        sscale = rsqrtf(tot / (float)DINNER + 1e-5f);
    }
    __syncthreads();
    float sc = sscale;
#pragma unroll
    for (int i = 0; i < 6; ++i) {
        int j = t + 256 * i;
        ybf[(long)row * DINNER + j] = f2bf(g[i] * sc * normw[j]);
    }
}

extern "C" void kernel_launch(void* const* d_in, const int* in_sizes, int n_in,
                              void* d_out, int out_size, void* d_ws, size_t ws_size,
                              hipStream_t stream) {
    const float* u = (const float*)d_in[0];
    const float* W_in = (const float*)d_in[1];
    const float* conv_w = (const float*)d_in[2];
    const float* conv_b = (const float*)d_in[3];
    const float* dt_bias = (const float*)d_in[4];
    const float* A_log = (const float*)d_in[5];
    const float* Dp = (const float*)d_in[6];
    const float* norm_w = (const float*)d_in[7];
    const float* W_out = (const float*)d_in[8];
    float* out = (float*)d_out;

    char* ws = (char*)d_ws;
    size_t off = 0;
    auto alloc = [&](size_t bytes) {
        void* p = ws + off;
        off += (bytes + 255) & ~(size_t)255;
        return p;
    };
    ushort_t* zbf = (ushort_t*)alloc((size_t)BROWS * DINNER * 2);      // 25.2 MB
    float* xbcraw = (float*)alloc((size_t)BROWS * XBCW * 4);           // 54.5 MB
    float* xbc = (float*)alloc((size_t)BROWS * XBCW * 4);              // 54.5 MB
    float* dtbT = (float*)alloc((size_t)NH * BROWS * 4);               // 0.79 MB
    float* acs = (float*)alloc((size_t)2 * NH * NCHUNK * 64 * 4);      // 0.79 MB
    float* Tsum = (float*)alloc((size_t)2 * NH * NCHUNK * 4);          // 12 KB
    ushort_t* states = (ushort_t*)alloc((size_t)2 * NH * NCHUNK * 4096 * 2);  // 25.2 MB
    ushort_t* ybuf = (ushort_t*)alloc((size_t)BROWS * DINNER * 2);     // 25.2 MB
    ushort_t* ybf = (ushort_t*)xbcraw;  // alias: xbcraw dead after conv

    if (off > ws_size) {
        fill_kernel<<<(out_size + 255) / 256, 256, 0, stream>>>(out, out_size, 12345.0f);
        return;
    }

    // in-projection with split epilogue (z bf16 / xBC f32 / dt softplus transposed)
    gemm_bt<1><<<dim3(26, 64), 256, 0, stream>>>(u, W_in, nullptr, DM, 0, DINPROJ,
                                                 zbf, xbcraw, dtbT, dt_bias);

    conv_kernel<<<dim3(BROWS, 7), 256, 0, stream>>>(xbcraw, conv_w, conv_b, xbc);

    acs_kernel<<<2 * NH, 256, 0, stream>>>(dtbT, A_log, acs, Tsum);
    states_kernel<<<dim3(NH, NCHUNK, 2), 256, 0, stream>>>(xbc, dtbT, acs, Tsum, states);
    scan_kernel<<<dim3(16, NH, 2), 256, 0, stream>>>(Tsum, states);
    yfull_kernel<<<dim3(NH, NCHUNK, 2), 256, 0, stream>>>(xbc, dtbT, acs, states, ybuf);

    norm_kernel<<<BROWS, 256, 0, stream>>>(ybuf, xbc, zbf, Dp, norm_w, ybf);

    // out-projection
    gemm_bt<0><<<dim3(6, 64), 256, 0, stream>>>(ybf, W_out, out, DINNER, DM, DM,
                                                nullptr, nullptr, nullptr, nullptr);
}

// Round 11
// 291.509 us; speedup vs baseline: 6.7556x; 1.1513x over previous
//
#include <hip/hip_runtime.h>

typedef __attribute__((ext_vector_type(4))) float f4;
typedef __attribute__((ext_vector_type(8))) short bfx8;
typedef __attribute__((ext_vector_type(4))) float f32x4;
typedef __attribute__((ext_vector_type(4))) unsigned int u32x4;
typedef __attribute__((ext_vector_type(4))) unsigned short u16x4;
typedef __attribute__((ext_vector_type(8))) unsigned short u16x8;
typedef unsigned short ushort_t;

#define DM 768
#define DINNER 1536
#define NH 24
#define XBCW 1664
#define DINPROJ 3224
#define NPAD1 3328
#define NCHUNK 64
#define BROWS 8192
#define PADB 72  // bf16 LDS row stride for 64-wide tiles

__device__ inline ushort_t f2bf(float f) {
    unsigned u = __builtin_bit_cast(unsigned, f);
    unsigned r = (u + 0x7FFF + ((u >> 16) & 1)) >> 16;
    return (ushort_t)r;
}
__device__ inline float bf2f(ushort_t u) {
    return __builtin_bit_cast(float, (unsigned)u << 16);
}
__device__ inline u32x4 pack8(f4 a, f4 b) {
    u32x4 o;
    o[0] = (unsigned)f2bf(a[0]) | ((unsigned)f2bf(a[1]) << 16);
    o[1] = (unsigned)f2bf(a[2]) | ((unsigned)f2bf(a[3]) << 16);
    o[2] = (unsigned)f2bf(b[0]) | ((unsigned)f2bf(b[1]) << 16);
    o[3] = (unsigned)f2bf(b[2]) | ((unsigned)f2bf(b[3]) << 16);
    return o;
}
// direct global->LDS 16B staging (no VGPR roundtrip). dst must be wave-uniform; HW adds lane*16.
__device__ inline void gl16(const void* g, void* l) {
    __builtin_amdgcn_global_load_lds((const __attribute__((address_space(1))) void*)g,
                                     (__attribute__((address_space(3))) void*)l, 16, 0, 0);
}

__global__ __launch_bounds__(256) void fill_kernel(float* out, int n, float v) {
    int i = blockIdx.x * 256 + threadIdx.x;
    if (i < n) out[i] = v;
}

// ---- f32 -> bf16 bulk convert ----
__global__ __launch_bounds__(256) void cvt_kernel(const float* __restrict__ in,
                                                  ushort_t* __restrict__ outp, long n4) {
    long i = (long)blockIdx.x * 256 + threadIdx.x;
    if (i >= n4) return;
    f4 v = *(const f4*)&in[i * 4];
    u16x4 o;
    o[0] = f2bf(v[0]); o[1] = f2bf(v[1]); o[2] = f2bf(v[2]); o[3] = f2bf(v[3]);
    *(u16x4*)&outp[i * 4] = o;
}

// ---- W_in f32 [3224][768] -> bf16 [3328][768], zero-padded rows ----
__global__ __launch_bounds__(256) void cvt_pad_kernel(const float* __restrict__ in,
                                                      ushort_t* __restrict__ outp) {
    long q = (long)blockIdx.x * 256 + threadIdx.x;  // quad index over 3328*192
    if (q >= (long)NPAD1 * 192) return;
    int row = (int)(q / 192);
    int cq = (int)(q % 192);
    u16x4 o = {0, 0, 0, 0};
    if (row < DINPROJ) {
        f4 v = *(const f4*)&in[(long)row * DM + cq * 4];
        o[0] = f2bf(v[0]); o[1] = f2bf(v[1]); o[2] = f2bf(v[2]); o[3] = f2bf(v[3]);
    }
    *(u16x4*)&outp[q * 4] = o;
}

// ---- GEMM C = A[M][K] * B[N][K]^T, bf16 inputs, global_load_lds staging.
// Grid exactly covers M/128 x N/128 (no bounds checks).
// EPI=0: C f32 dense (out-proj). EPI=1: split epilogue (in-proj).
template <int EPI>
__global__ __launch_bounds__(256) void gemm_bt(const ushort_t* __restrict__ A,
                                               const ushort_t* __restrict__ B,
                                               float* __restrict__ C,
                                               int K, int ldc,
                                               ushort_t* __restrict__ zbf,
                                               float* __restrict__ xbcraw,
                                               float* __restrict__ dtbT,
                                               const float* __restrict__ dt_bias) {
    __shared__ __align__(16) ushort_t As[128 * 32];
    __shared__ __align__(16) ushort_t Bs[128 * 32];
    int tid = threadIdx.x;
    int lane = tid & 63;
    int w = tid >> 6;
    int wr = w >> 1, wc = w & 1;
    int m0 = blockIdx.y * 128;
    int n0 = blockIdx.x * 128;
    int r16 = lane & 15, kg = lane >> 4;

    // staging geometry: chunk = tid + 256*r; row = chunk>>2; col8 = (chunk&3)*8
    int row0 = tid >> 2, cof0 = (tid & 3) * 8;
    int row1 = (tid + 256) >> 2, cof1 = (tid & 3) * 8;
    const ushort_t* a0 = &A[(long)(m0 + row0) * K + cof0];
    const ushort_t* a1 = &A[(long)(m0 + row1) * K + cof1];
    const ushort_t* b0 = &B[(long)(n0 + row0) * K + cof0];
    const ushort_t* b1 = &B[(long)(n0 + row1) * K + cof1];
    char* asb = (char*)As + w * 1024;  // wave-uniform LDS dest base
    char* bsb = (char*)Bs + w * 1024;

    f32x4 acc[4][4] = {};

    for (int k0 = 0; k0 < K; k0 += 32) {
        gl16(a0 + k0, asb);
        gl16(a1 + k0, asb + 4096);
        gl16(b0 + k0, bsb);
        gl16(b1 + k0, bsb + 4096);
        __syncthreads();  // drains vmcnt -> LDS tiles ready
        bfx8 af[4], bfr[4];
#pragma unroll
        for (int i = 0; i < 4; ++i) {
            af[i] = *(const bfx8*)&As[(wr * 64 + i * 16 + r16) * 32 + kg * 8];
            bfr[i] = *(const bfx8*)&Bs[(wc * 64 + i * 16 + r16) * 32 + kg * 8];
        }
#pragma unroll
        for (int i = 0; i < 4; ++i)
#pragma unroll
            for (int j = 0; j < 4; ++j)
                acc[i][j] = __builtin_amdgcn_mfma_f32_16x16x32_bf16(af[i], bfr[j], acc[i][j], 0, 0, 0);
        __syncthreads();  // reads done before next stage overwrites
    }

#pragma unroll
    for (int i = 0; i < 4; ++i) {
        int rowb = m0 + wr * 64 + i * 16 + kg * 4;
#pragma unroll
        for (int j = 0; j < 4; ++j) {
            int col = n0 + wc * 64 + j * 16 + r16;
            if (EPI == 0) {
#pragma unroll
                for (int q = 0; q < 4; ++q)
                    C[(long)(rowb + q) * ldc + col] = acc[i][j][q];
            } else {
                if (n0 < DINNER) {  // z -> bf16
#pragma unroll
                    for (int q = 0; q < 4; ++q)
                        zbf[(long)(rowb + q) * DINNER + col] = f2bf(acc[i][j][q]);
                } else if (n0 < 3200) {  // xBC raw -> f32
#pragma unroll
                    for (int q = 0; q < 4; ++q)
                        xbcraw[(long)(rowb + q) * XBCW + col - DINNER] = acc[i][j][q];
                } else if (col < DINPROJ) {  // dt -> softplus -> transposed
                    int h = col - 3200;
                    float bias = dt_bias[h];
#pragma unroll
                    for (int q = 0; q < 4; ++q) {
                        float v = acc[i][j][q] + bias;
                        float d = (v > 20.f) ? v : log1pf(__expf(v));
                        dtbT[(long)h * BROWS + rowb + q] = d;
                    }
                }
            }
        }
    }
}

// ---- depthwise causal conv(4) + bias + silu (dense in/out) ----
__global__ __launch_bounds__(256) void conv_kernel(const float* __restrict__ xin,
                                                   const float* __restrict__ cw,
                                                   const float* __restrict__ cb,
                                                   float* __restrict__ xbc) {
    int ch = blockIdx.y * 256 + threadIdx.x;
    int row = blockIdx.x;
    if (ch >= XBCW) return;
    int b = row >> 12;
    int l = row & 4095;
    float acc = cb[ch];
#pragma unroll
    for (int k = 0; k < 4; ++k) {
        int ll = l - 3 + k;
        if (ll >= 0)
            acc += cw[ch * 4 + k] * xin[(long)(b * 4096 + ll) * XBCW + ch];
    }
    float s = acc / (1.f + __expf(-acc));
    xbc[(long)row * XBCW + ch] = s;
}

// ---- per-chunk cumsum of A*dt via wave scan ----
__global__ __launch_bounds__(256) void acs_kernel(const float* __restrict__ dtbT,
                                                  const float* __restrict__ A_log,
                                                  float* __restrict__ acs,
                                                  float* __restrict__ Tsum) {
    int bh = blockIdx.x;  // b*24+h
    int b = bh / NH, h = bh % NH;
    int t = threadIdx.x;
    int lane = t & 63;
    float A = -__expf(A_log[h]);
    const float* dp = &dtbT[(long)h * BROWS + b * 4096];
#pragma unroll
    for (int it = 0; it < 16; ++it) {
        int c = (t >> 6) + 4 * it;
        float v = A * dp[c * 64 + lane];
#pragma unroll
        for (int off = 1; off < 64; off <<= 1) {
            float u = __shfl_up(v, off, 64);
            if (lane >= off) v += u;
        }
        acs[((long)bh * NCHUNK + c) * 64 + lane] = v;
        if (lane == 63) Tsum[bh * NCHUNK + c] = v;
    }
}

// ---- phase A (MFMA): states[p][n] = sum_l (x*dt*decay)[l][p] * B[l][n] -> bf16 ----
__global__ __launch_bounds__(256) void states_kernel(const float* __restrict__ xbc,
                                                     const float* __restrict__ dtbT,
                                                     const float* __restrict__ acs,
                                                     const float* __restrict__ Tsum,
                                                     ushort_t* __restrict__ states) {
    int h = blockIdx.x, c = blockIdx.y, b = blockIdx.z;
    __shared__ __align__(16) ushort_t Wt[64 * PADB];  // wT[p][l], then output tile [p][n]
    __shared__ __align__(16) ushort_t Bt[64 * PADB];  // BT[n][l]
    int t = threadIdx.x;
    long rowg0 = (long)b * 4096 + c * 64;
    long acsb = ((long)(b * NH + h) * NCHUNK + c) * 64;
    float T = Tsum[(b * NH + h) * NCHUNK + c];
#pragma unroll
    for (int i = 0; i < 2; ++i) {
        int q = t + 256 * i;
        int l = q >> 3, sg = q & 7;
        const float* rp = &xbc[(rowg0 + l) * (long)XBCW];
        float dec = dtbT[(long)h * BROWS + rowg0 + l] * __expf(T - acs[acsb + l]);
        f4 x0 = *(const f4*)&rp[h * 64 + sg * 8];
        f4 x1 = *(const f4*)&rp[h * 64 + sg * 8 + 4];
        f4 b0 = *(const f4*)&rp[DINNER + sg * 8];
        f4 b1 = *(const f4*)&rp[DINNER + sg * 8 + 4];
#pragma unroll
        for (int jj = 0; jj < 4; ++jj) {
            Wt[(sg * 8 + jj) * PADB + l] = f2bf(x0[jj] * dec);
            Wt[(sg * 8 + 4 + jj) * PADB + l] = f2bf(x1[jj] * dec);
            Bt[(sg * 8 + jj) * PADB + l] = f2bf(b0[jj]);
            Bt[(sg * 8 + 4 + jj) * PADB + l] = f2bf(b1[jj]);
        }
    }
    __syncthreads();
    int w = t >> 6, lane = t & 63;
    int r16 = lane & 15, kg = lane >> 4;
    bfx8 aw[2];
#pragma unroll
    for (int kk = 0; kk < 2; ++kk)
        aw[kk] = *(const bfx8*)&Wt[(w * 16 + r16) * PADB + kk * 32 + kg * 8];
    f32x4 acc[4] = {};
#pragma unroll
    for (int j = 0; j < 4; ++j)
#pragma unroll
        for (int kk = 0; kk < 2; ++kk) {
            bfx8 bb = *(const bfx8*)&Bt[(j * 16 + r16) * PADB + kk * 32 + kg * 8];
            acc[j] = __builtin_amdgcn_mfma_f32_16x16x32_bf16(aw[kk], bb, acc[j], 0, 0, 0);
        }
    __syncthreads();
#pragma unroll
    for (int j = 0; j < 4; ++j)
#pragma unroll
        for (int q = 0; q < 4; ++q)
            Wt[(w * 16 + kg * 4 + q) * PADB + j * 16 + r16] = f2bf(acc[j][q]);
    __syncthreads();
    long ob = ((long)(b * NH + h) * NCHUNK + c) * 4096;
#pragma unroll
    for (int i = 0; i < 2; ++i) {
        int q = t + 256 * i;
        int p = q >> 3, sg = q & 7;
        *(u16x8*)&states[ob + p * 64 + sg * 8] = *(const u16x8*)&Wt[p * PADB + sg * 8];
    }
}

// ---- sequential chunk scan ----
__global__ __launch_bounds__(256) void scan_kernel(const float* __restrict__ Tsum,
                                                   ushort_t* __restrict__ states) {
    int e = blockIdx.x * 256 + threadIdx.x;
    int h = blockIdx.y, b = blockIdx.z;
    long base = ((long)(b * NH + h)) * NCHUNK * 4096 + e;
    const float* Tp = &Tsum[(b * NH + h) * NCHUNK];
    float acc = 0.f;
    for (int c = 0; c < NCHUNK; ++c) {
        float cur = bf2f(states[base + (long)c * 4096]);
        states[base + (long)c * 4096] = f2bf(acc);
        acc = __expf(Tp[c]) * acc + cur;
    }
}

// ---- phase C (MFMA): Y = (C.B^T . Lm) @ xd + exp(acs) * (C @ Sprev^T) -> bf16 ybuf ----
__global__ __launch_bounds__(256) void yfull_kernel(const float* __restrict__ xbc,
                                                    const float* __restrict__ dtbT,
                                                    const float* __restrict__ acs,
                                                    const ushort_t* __restrict__ sprev,
                                                    ushort_t* __restrict__ ybuf) {
    int h = blockIdx.x, c = blockIdx.y, b = blockIdx.z;
    __shared__ __align__(16) ushort_t Cb[64 * PADB];  // C[l][n]
    __shared__ __align__(16) ushort_t Bb[64 * PADB];  // B[s][n], later output tile [l][p]
    __shared__ __align__(16) ushort_t Xt[64 * PADB];  // xd^T[p][s]
    __shared__ __align__(16) ushort_t Sp[64 * PADB];  // sprev[p][n]
    __shared__ __align__(16) ushort_t Sm[64 * PADB];  // masked scores [l][s]
    __shared__ float sAcs[64], sE[64];
    int t = threadIdx.x;
    long rowg0 = (long)b * 4096 + c * 64;
    long acsb = ((long)(b * NH + h) * NCHUNK + c) * 64;
    long spb = ((long)(b * NH + h) * NCHUNK + c) * 4096;
    if (t < 64) {
        float a = acs[acsb + t];
        sAcs[t] = a;
        sE[t] = __expf(a);
    }
#pragma unroll
    for (int i = 0; i < 2; ++i) {
        int q = t + 256 * i;
        int l = q >> 3, sg = q & 7;
        const float* rp = &xbc[(rowg0 + l) * (long)XBCW];
        f4 c0 = *(const f4*)&rp[1600 + sg * 8];
        f4 c1 = *(const f4*)&rp[1600 + sg * 8 + 4];
        *(u32x4*)&Cb[l * PADB + sg * 8] = pack8(c0, c1);
        f4 b0 = *(const f4*)&rp[DINNER + sg * 8];
        f4 b1 = *(const f4*)&rp[DINNER + sg * 8 + 4];
        *(u32x4*)&Bb[l * PADB + sg * 8] = pack8(b0, b1);
        float dtv = dtbT[(long)h * BROWS + rowg0 + l];
        f4 x0 = *(const f4*)&rp[h * 64 + sg * 8];
        f4 x1 = *(const f4*)&rp[h * 64 + sg * 8 + 4];
#pragma unroll
        for (int jj = 0; jj < 4; ++jj) {
            Xt[(sg * 8 + jj) * PADB + l] = f2bf(x0[jj] * dtv);
            Xt[(sg * 8 + 4 + jj) * PADB + l] = f2bf(x1[jj] * dtv);
        }
        *(u16x8*)&Sp[l * PADB + sg * 8] = *(const u16x8*)&sprev[spb + l * 64 + sg * 8];
    }
    __syncthreads();
    int w = t >> 6, lane = t & 63;
    int r16 = lane & 15, kg = lane >> 4;
    // phase 1: S = C.B^T (rows l in [16w,16w+16))
    bfx8 ac[2];
#pragma unroll
    for (int kk = 0; kk < 2; ++kk)
        ac[kk] = *(const bfx8*)&Cb[(w * 16 + r16) * PADB + kk * 32 + kg * 8];
    f32x4 s_acc[4] = {};
#pragma unroll
    for (int j = 0; j < 4; ++j)
#pragma unroll
        for (int kk = 0; kk < 2; ++kk) {
            bfx8 bb = *(const bfx8*)&Bb[(j * 16 + r16) * PADB + kk * 32 + kg * 8];
            s_acc[j] = __builtin_amdgcn_mfma_f32_16x16x32_bf16(ac[kk], bb, s_acc[j], 0, 0, 0);
        }
    // mask + decay -> Sm (bf16)
#pragma unroll
    for (int j = 0; j < 4; ++j)
#pragma unroll
        for (int q = 0; q < 4; ++q) {
            int l = w * 16 + kg * 4 + q;
            int s = j * 16 + r16;
            float v = s_acc[j][q];
            v = (s <= l) ? v * __expf(sAcs[l] - sAcs[s]) : 0.f;
            Sm[l * PADB + s] = f2bf(v);
        }
    __syncthreads();
    // phase 2: Yd = Sm @ xd (B-op = Xt[p][s]);  phase 3: Yo = C @ Sprev^T (B-op = Sp[p][n])
    bfx8 as[2];
#pragma unroll
    for (int kk = 0; kk < 2; ++kk)
        as[kk] = *(const bfx8*)&Sm[(w * 16 + r16) * PADB + kk * 32 + kg * 8];
    f32x4 d_acc[4] = {}, o_acc[4] = {};
#pragma unroll
    for (int j = 0; j < 4; ++j)
#pragma unroll
        for (int kk = 0; kk < 2; ++kk) {
            bfx8 xb = *(const bfx8*)&Xt[(j * 16 + r16) * PADB + kk * 32 + kg * 8];
            d_acc[j] = __builtin_amdgcn_mfma_f32_16x16x32_bf16(as[kk], xb, d_acc[j], 0, 0, 0);
            bfx8 sb = *(const bfx8*)&Sp[(j * 16 + r16) * PADB + kk * 32 + kg * 8];
            o_acc[j] = __builtin_amdgcn_mfma_f32_16x16x32_bf16(ac[kk], sb, o_acc[j], 0, 0, 0);
        }
    // epilogue tile -> Bb (dead), then coalesced copy out
#pragma unroll
    for (int j = 0; j < 4; ++j)
#pragma unroll
        for (int q = 0; q < 4; ++q) {
            int l = w * 16 + kg * 4 + q;
            int p = j * 16 + r16;
            Bb[l * PADB + p] = f2bf(d_acc[j][q] + sE[l] * o_acc[j][q]);
        }
    __syncthreads();
#pragma unroll
    for (int i = 0; i < 2; ++i) {
        int q = t + 256 * i;
        int l = q >> 3, sg = q & 7;
        *(u16x8*)&ybuf[(rowg0 + l) * (long)DINNER + h * 64 + sg * 8] =
            *(const u16x8*)&Bb[l * PADB + sg * 8];
    }
}

// ---- gated RMS norm -> bf16 ----
__global__ __launch_bounds__(256) void norm_kernel(const ushort_t* __restrict__ ybuf,
                                                   const float* __restrict__ xbc,
                                                   const ushort_t* __restrict__ zbf,
                                                   const float* __restrict__ Dp,
                                                   const float* __restrict__ normw,
                                                   ushort_t* __restrict__ ybf) {
    int row = blockIdx.x;
    int t = threadIdx.x;
    float g[6];
    float ss = 0.f;
#pragma unroll
    for (int i = 0; i < 6; ++i) {
        int j = t + 256 * i;
        int h = j >> 6;
        float x = xbc[(long)row * XBCW + j];
        float yy = bf2f(ybuf[(long)row * DINNER + j]) + x * Dp[h];
        float z = bf2f(zbf[(long)row * DINNER + j]);
        float gz = z / (1.f + __expf(-z));
        float v = yy * gz;
        g[i] = v;
        ss += v * v;
    }
#pragma unroll
    for (int o = 32; o > 0; o >>= 1) ss += __shfl_xor(ss, o, 64);
    __shared__ float wsum[4];
    __shared__ float sscale;
    int w = t >> 6;
    if ((t & 63) == 0) wsum[w] = ss;
    __syncthreads();
    if (t == 0) {
        float tot = wsum[0] + wsum[1] + wsum[2] + wsum[3];
        sscale = rsqrtf(tot / (float)DINNER + 1e-5f);
    }
    __syncthreads();
    float sc = sscale;
#pragma unroll
    for (int i = 0; i < 6; ++i) {
        int j = t + 256 * i;
        ybf[(long)row * DINNER + j] = f2bf(g[i] * sc * normw[j]);
    }
}

extern "C" void kernel_launch(void* const* d_in, const int* in_sizes, int n_in,
                              void* d_out, int out_size, void* d_ws, size_t ws_size,
                              hipStream_t stream) {
    const float* u = (const float*)d_in[0];
    const float* W_in = (const float*)d_in[1];
    const float* conv_w = (const float*)d_in[2];
    const float* conv_b = (const float*)d_in[3];
    const float* dt_bias = (const float*)d_in[4];
    const float* A_log = (const float*)d_in[5];
    const float* Dp = (const float*)d_in[6];
    const float* norm_w = (const float*)d_in[7];
    const float* W_out = (const float*)d_in[8];
    float* out = (float*)d_out;

    char* ws = (char*)d_ws;
    size_t off = 0;
    auto alloc = [&](size_t bytes) {
        void* p = ws + off;
        off += (bytes + 255) & ~(size_t)255;
        return p;
    };
    ushort_t* zbf = (ushort_t*)alloc((size_t)BROWS * DINNER * 2);      // 25.2 MB
    float* xbcraw = (float*)alloc((size_t)BROWS * XBCW * 4);           // 54.5 MB
    float* xbc = (float*)alloc((size_t)BROWS * XBCW * 4);              // 54.5 MB
    float* dtbT = (float*)alloc((size_t)NH * BROWS * 4);               // 0.79 MB
    float* acs = (float*)alloc((size_t)2 * NH * NCHUNK * 64 * 4);      // 0.79 MB
    float* Tsum = (float*)alloc((size_t)2 * NH * NCHUNK * 4);          // 12 KB
    ushort_t* states = (ushort_t*)alloc((size_t)2 * NH * NCHUNK * 4096 * 2);  // 25.2 MB
    ushort_t* ybuf = (ushort_t*)alloc((size_t)BROWS * DINNER * 2);     // 25.2 MB
    // aliases with disjoint lifetimes:
    ushort_t* ybf = (ushort_t*)xbcraw;    // xbcraw dead after conv
    ushort_t* ubf = ybuf;                 // u-bf16 dead after gemm1; ybuf written in yfull
    ushort_t* winbf = states;             // W_in-bf16 dead after gemm1; states written after
    ushort_t* woutbf = states;            // W_out-bf16 written after yfull consumed states

    if (off > ws_size) {
        fill_kernel<<<(out_size + 255) / 256, 256, 0, stream>>>(out, out_size, 12345.0f);
        return;
    }

    // pre-convert inputs to bf16 (same rounding as previous in-GEMM pack8)
    cvt_kernel<<<(BROWS * DM / 4 + 255) / 256, 256, 0, stream>>>(u, ubf, (long)BROWS * DM / 4);
    cvt_pad_kernel<<<((long)NPAD1 * 192 + 255) / 256, 256, 0, stream>>>(W_in, winbf);

    // in-projection with split epilogue (z bf16 / xBC f32 / dt softplus transposed)
    gemm_bt<1><<<dim3(26, 64), 256, 0, stream>>>(ubf, winbf, nullptr, DM, 0,
                                                 zbf, xbcraw, dtbT, dt_bias);

    conv_kernel<<<dim3(BROWS, 7), 256, 0, stream>>>(xbcraw, conv_w, conv_b, xbc);

    acs_kernel<<<2 * NH, 256, 0, stream>>>(dtbT, A_log, acs, Tsum);
    states_kernel<<<dim3(NH, NCHUNK, 2), 256, 0, stream>>>(xbc, dtbT, acs, Tsum, states);
    scan_kernel<<<dim3(16, NH, 2), 256, 0, stream>>>(Tsum, states);
    yfull_kernel<<<dim3(NH, NCHUNK, 2), 256, 0, stream>>>(xbc, dtbT, acs, states, ybuf);

    norm_kernel<<<BROWS, 256, 0, stream>>>(ybuf, xbc, zbf, Dp, norm_w, ybf);

    // W_out -> bf16 into states region (dead after yfull), then out-projection
    cvt_kernel<<<(DM * DINNER / 4 + 255) / 256, 256, 0, stream>>>(W_out, woutbf, (long)DM * DINNER / 4);
    gemm_bt<0><<<dim3(6, 64), 256, 0, stream>>>(ybf, woutbf, out, DINNER, DM,
                                                nullptr, nullptr, nullptr, nullptr);
}

// Round 13
// 280.218 us; speedup vs baseline: 7.0278x; 1.0403x over previous
//
#include <hip/hip_runtime.h>

typedef __attribute__((ext_vector_type(4))) float f4;
typedef __attribute__((ext_vector_type(8))) short bfx8;
typedef __attribute__((ext_vector_type(4))) float f32x4;
typedef __attribute__((ext_vector_type(4))) unsigned int u32x4;
typedef __attribute__((ext_vector_type(4))) unsigned short u16x4;
typedef __attribute__((ext_vector_type(8))) unsigned short u16x8;
typedef unsigned short ushort_t;

#define DM 768
#define DINNER 1536
#define NH 24
#define XBCW 1664
#define DINPROJ 3224
#define NPAD1 3328
#define NCHUNK 64
#define BROWS 8192
#define PADB 72  // bf16 LDS row stride for 64-wide tiles

__device__ inline ushort_t f2bf(float f) {
    unsigned u = __builtin_bit_cast(unsigned, f);
    unsigned r = (u + 0x7FFF + ((u >> 16) & 1)) >> 16;
    return (ushort_t)r;
}
__device__ inline float bf2f(ushort_t u) {
    return __builtin_bit_cast(float, (unsigned)u << 16);
}
// direct global->LDS 16B staging. dst wave-uniform; HW adds lane*16.
__device__ inline void gl16(const void* g, void* l) {
    __builtin_amdgcn_global_load_lds((const __attribute__((address_space(1))) void*)g,
                                     (__attribute__((address_space(3))) void*)l, 16, 0, 0);
}

__global__ __launch_bounds__(256) void fill_kernel(float* out, int n, float v) {
    int i = blockIdx.x * 256 + threadIdx.x;
    if (i < n) out[i] = v;
}

// ---- f32 -> bf16 bulk convert ----
__global__ __launch_bounds__(256) void cvt_kernel(const float* __restrict__ in,
                                                  ushort_t* __restrict__ outp, long n4) {
    long i = (long)blockIdx.x * 256 + threadIdx.x;
    if (i >= n4) return;
    f4 v = *(const f4*)&in[i * 4];
    u16x4 o;
    o[0] = f2bf(v[0]); o[1] = f2bf(v[1]); o[2] = f2bf(v[2]); o[3] = f2bf(v[3]);
    *(u16x4*)&outp[i * 4] = o;
}

// ---- W_in f32 [3224][768] -> bf16 [3328][768], zero-padded rows ----
__global__ __launch_bounds__(256) void cvt_pad_kernel(const float* __restrict__ in,
                                                      ushort_t* __restrict__ outp) {
    long q = (long)blockIdx.x * 256 + threadIdx.x;
    if (q >= (long)NPAD1 * 192) return;
    int row = (int)(q / 192);
    int cq = (int)(q % 192);
    u16x4 o = {0, 0, 0, 0};
    if (row < DINPROJ) {
        f4 v = *(const f4*)&in[(long)row * DM + cq * 4];
        o[0] = f2bf(v[0]); o[1] = f2bf(v[1]); o[2] = f2bf(v[2]); o[3] = f2bf(v[3]);
    }
    *(u16x4*)&outp[q * 4] = o;
}

// ---- GEMM C = A[M][K] * B[N][K]^T, bf16 in, 2-phase double-buffered gl16 staging.
// EPI=0: C f32 dense (out-proj). EPI=1: split epilogue (in-proj).
template <int EPI>
__global__ __launch_bounds__(256) void gemm_bt(const ushort_t* __restrict__ A,
                                               const ushort_t* __restrict__ B,
                                               float* __restrict__ C,
                                               int K, int ldc,
                                               ushort_t* __restrict__ zbf,
                                               float* __restrict__ xbcraw,
                                               float* __restrict__ dtbT,
                                               const float* __restrict__ dt_bias) {
    __shared__ __align__(16) ushort_t As[2][128 * 32];  // 8KB each
    __shared__ __align__(16) ushort_t Bs[2][128 * 32];
    int tid = threadIdx.x;
    int lane = tid & 63;
    int w = tid >> 6;
    int wr = w >> 1, wc = w & 1;
    int m0 = blockIdx.y * 128;
    int n0 = blockIdx.x * 128;
    int r16 = lane & 15, kg = lane >> 4;

    int row0 = tid >> 2, cof0 = (tid & 3) * 8;
    const ushort_t* a0 = &A[(long)(m0 + row0) * K + cof0];
    const ushort_t* a1 = &A[(long)(m0 + row0 + 64) * K + cof0];
    const ushort_t* b0 = &B[(long)(n0 + row0) * K + cof0];
    const ushort_t* b1 = &B[(long)(n0 + row0 + 64) * K + cof0];
    char* asb[2] = {(char*)&As[0][0] + w * 1024, (char*)&As[1][0] + w * 1024};
    char* bsb[2] = {(char*)&Bs[0][0] + w * 1024, (char*)&Bs[1][0] + w * 1024};

    f32x4 acc[4][4] = {};

    // prologue: stage tile 0 into buf 0, drain, barrier
    gl16(a0, asb[0]); gl16(a1, asb[0] + 4096);
    gl16(b0, bsb[0]); gl16(b1, bsb[0] + 4096);
    asm volatile("s_waitcnt vmcnt(0)" ::: "memory");
    __builtin_amdgcn_s_barrier();

    int nk = K >> 5;
    for (int t = 0; t < nk; ++t) {
        int cur = t & 1;
        if (t + 1 < nk) {  // prefetch next tile into other buffer (flies under MFMA)
            int k1 = (t + 1) << 5;
            gl16(a0 + k1, asb[cur ^ 1]); gl16(a1 + k1, asb[cur ^ 1] + 4096);
            gl16(b0 + k1, bsb[cur ^ 1]); gl16(b1 + k1, bsb[cur ^ 1] + 4096);
        }
        const ushort_t* Asc = &As[cur][0];
        const ushort_t* Bsc = &Bs[cur][0];
        bfx8 af[4], bfr[4];
#pragma unroll
        for (int i = 0; i < 4; ++i) {
            af[i] = *(const bfx8*)&Asc[(wr * 64 + i * 16 + r16) * 32 + kg * 8];
            bfr[i] = *(const bfx8*)&Bsc[(wc * 64 + i * 16 + r16) * 32 + kg * 8];
        }
#pragma unroll
        for (int i = 0; i < 4; ++i)
#pragma unroll
            for (int j = 0; j < 4; ++j)
                acc[i][j] = __builtin_amdgcn_mfma_f32_16x16x32_bf16(af[i], bfr[j], acc[i][j], 0, 0, 0);
        // drain own prefetch + LDS reads, then single barrier per K-step
        asm volatile("s_waitcnt vmcnt(0) lgkmcnt(0)" ::: "memory");
        __builtin_amdgcn_sched_barrier(0);
        __builtin_amdgcn_s_barrier();
    }

#pragma unroll
    for (int i = 0; i < 4; ++i) {
        int rowb = m0 + wr * 64 + i * 16 + kg * 4;
#pragma unroll
        for (int j = 0; j < 4; ++j) {
            int col = n0 + wc * 64 + j * 16 + r16;
            if (EPI == 0) {
#pragma unroll
                for (int q = 0; q < 4; ++q)
                    C[(long)(rowb + q) * ldc + col] = acc[i][j][q];
            } else {
                if (n0 < DINNER) {  // z -> bf16
#pragma unroll
                    for (int q = 0; q < 4; ++q)
                        zbf[(long)(rowb + q) * DINNER + col] = f2bf(acc[i][j][q]);
                } else if (n0 < 3200) {  // xBC raw -> f32
#pragma unroll
                    for (int q = 0; q < 4; ++q)
                        xbcraw[(long)(rowb + q) * XBCW + col - DINNER] = acc[i][j][q];
                } else if (col < DINPROJ) {  // dt -> softplus -> transposed
                    int h = col - 3200;
                    float bias = dt_bias[h];
#pragma unroll
                    for (int q = 0; q < 4; ++q) {
                        float v = acc[i][j][q] + bias;
                        float d = (v > 20.f) ? v : log1pf(__expf(v));
                        dtbT[(long)h * BROWS + rowb + q] = d;
                    }
                }
            }
        }
    }
}

// ---- depthwise causal conv(4) + bias + silu; f32 in, bf16 out ----
__global__ __launch_bounds__(256) void conv_kernel(const float* __restrict__ xin,
                                                   const float* __restrict__ cw,
                                                   const float* __restrict__ cb,
                                                   ushort_t* __restrict__ xbc) {
    int ch = blockIdx.y * 256 + threadIdx.x;
    int row = blockIdx.x;
    if (ch >= XBCW) return;
    int b = row >> 12;
    int l = row & 4095;
    float acc = cb[ch];
#pragma unroll
    for (int k = 0; k < 4; ++k) {
        int ll = l - 3 + k;
        if (ll >= 0)
            acc += cw[ch * 4 + k] * xin[(long)(b * 4096 + ll) * XBCW + ch];
    }
    float s = acc / (1.f + __expf(-acc));
    xbc[(long)row * XBCW + ch] = f2bf(s);
}

// ---- per-chunk cumsum of A*dt via wave scan ----
__global__ __launch_bounds__(256) void acs_kernel(const float* __restrict__ dtbT,
                                                  const float* __restrict__ A_log,
                                                  float* __restrict__ acs,
                                                  float* __restrict__ Tsum) {
    int bh = blockIdx.x;
    int b = bh / NH, h = bh % NH;
    int t = threadIdx.x;
    int lane = t & 63;
    float A = -__expf(A_log[h]);
    const float* dp = &dtbT[(long)h * BROWS + b * 4096];
#pragma unroll
    for (int it = 0; it < 16; ++it) {
        int c = (t >> 6) + 4 * it;
        float v = A * dp[c * 64 + lane];
#pragma unroll
        for (int off = 1; off < 64; off <<= 1) {
            float u = __shfl_up(v, off, 64);
            if (lane >= off) v += u;
        }
        acs[((long)bh * NCHUNK + c) * 64 + lane] = v;
        if (lane == 63) Tsum[bh * NCHUNK + c] = v;
    }
}

// ---- phase A (MFMA): states[p][n] = sum_l (x*dt*decay)[l][p] * B[l][n] -> bf16 ----
__global__ __launch_bounds__(256) void states_kernel(const ushort_t* __restrict__ xbc,
                                                     const float* __restrict__ dtbT,
                                                     const float* __restrict__ acs,
                                                     const float* __restrict__ Tsum,
                                                     ushort_t* __restrict__ states) {
    int h = blockIdx.x, c = blockIdx.y, b = blockIdx.z;
    __shared__ __align__(16) ushort_t Wt[64 * PADB];
    __shared__ __align__(16) ushort_t Bt[64 * PADB];
    int t = threadIdx.x;
    long rowg0 = (long)b * 4096 + c * 64;
    long acsb = ((long)(b * NH + h) * NCHUNK + c) * 64;
    float T = Tsum[(b * NH + h) * NCHUNK + c];
#pragma unroll
    for (int i = 0; i < 2; ++i) {
        int q = t + 256 * i;
        int l = q >> 3, sg = q & 7;
        const ushort_t* rp = &xbc[(rowg0 + l) * (long)XBCW];
        float dec = dtbT[(long)h * BROWS + rowg0 + l] * __expf(T - acs[acsb + l]);
        u16x8 xv = *(const u16x8*)&rp[h * 64 + sg * 8];
        u16x8 bv = *(const u16x8*)&rp[DINNER + sg * 8];
#pragma unroll
        for (int jj = 0; jj < 8; ++jj) {
            Wt[(sg * 8 + jj) * PADB + l] = f2bf(bf2f(xv[jj]) * dec);
            Bt[(sg * 8 + jj) * PADB + l] = bv[jj];
        }
    }
    __syncthreads();
    int w = t >> 6, lane = t & 63;
    int r16 = lane & 15, kg = lane >> 4;
    bfx8 aw[2];
#pragma unroll
    for (int kk = 0; kk < 2; ++kk)
        aw[kk] = *(const bfx8*)&Wt[(w * 16 + r16) * PADB + kk * 32 + kg * 8];
    f32x4 acc[4] = {};
#pragma unroll
    for (int j = 0; j < 4; ++j)
#pragma unroll
        for (int kk = 0; kk < 2; ++kk) {
            bfx8 bb = *(const bfx8*)&Bt[(j * 16 + r16) * PADB + kk * 32 + kg * 8];
            acc[j] = __builtin_amdgcn_mfma_f32_16x16x32_bf16(aw[kk], bb, acc[j], 0, 0, 0);
        }
    __syncthreads();
#pragma unroll
    for (int j = 0; j < 4; ++j)
#pragma unroll
        for (int q = 0; q < 4; ++q)
            Wt[(w * 16 + kg * 4 + q) * PADB + j * 16 + r16] = f2bf(acc[j][q]);
    __syncthreads();
    long ob = ((long)(b * NH + h) * NCHUNK + c) * 4096;
#pragma unroll
    for (int i = 0; i < 2; ++i) {
        int q = t + 256 * i;
        int p = q >> 3, sg = q & 7;
        *(u16x8*)&states[ob + p * 64 + sg * 8] = *(const u16x8*)&Wt[p * PADB + sg * 8];
    }
}

// ---- sequential chunk scan ----
__global__ __launch_bounds__(256) void scan_kernel(const float* __restrict__ Tsum,
                                                   ushort_t* __restrict__ states) {
    int e = blockIdx.x * 256 + threadIdx.x;
    int h = blockIdx.y, b = blockIdx.z;
    long base = ((long)(b * NH + h)) * NCHUNK * 4096 + e;
    const float* Tp = &Tsum[(b * NH + h) * NCHUNK];
    float acc = 0.f;
    for (int c = 0; c < NCHUNK; ++c) {
        float cur = bf2f(states[base + (long)c * 4096]);
        states[base + (long)c * 4096] = f2bf(acc);
        acc = __expf(Tp[c]) * acc + cur;
    }
}

// ---- phase C (MFMA): Y = (C.B^T . Lm) @ xd + exp(acs) * (C @ Sprev^T) -> bf16 ybuf ----
__global__ __launch_bounds__(256) void yfull_kernel(const ushort_t* __restrict__ xbc,
                                                    const float* __restrict__ dtbT,
                                                    const float* __restrict__ acs,
                                                    const ushort_t* __restrict__ sprev,
                                                    ushort_t* __restrict__ ybuf) {
    int h = blockIdx.x, c = blockIdx.y, b = blockIdx.z;
    __shared__ __align__(16) ushort_t Cb[64 * PADB];  // C[l][n]
    __shared__ __align__(16) ushort_t Bb[64 * PADB];  // B[s][n], later output tile [l][p]
    __shared__ __align__(16) ushort_t Xt[64 * PADB];  // xd^T[p][s]
    __shared__ __align__(16) ushort_t Sp[64 * PADB];  // sprev[p][n]
    __shared__ __align__(16) ushort_t Sm[64 * PADB];  // masked scores [l][s]
    __shared__ float sAcs[64], sE[64];
    int t = threadIdx.x;
    long rowg0 = (long)b * 4096 + c * 64;
    long acsb = ((long)(b * NH + h) * NCHUNK + c) * 64;
    long spb = ((long)(b * NH + h) * NCHUNK + c) * 4096;
    if (t < 64) {
        float a = acs[acsb + t];
        sAcs[t] = a;
        sE[t] = __expf(a);
    }
#pragma unroll
    for (int i = 0; i < 2; ++i) {
        int q = t + 256 * i;
        int l = q >> 3, sg = q & 7;
        const ushort_t* rp = &xbc[(rowg0 + l) * (long)XBCW];
        *(u16x8*)&Cb[l * PADB + sg * 8] = *(const u16x8*)&rp[1600 + sg * 8];
        *(u16x8*)&Bb[l * PADB + sg * 8] = *(const u16x8*)&rp[DINNER + sg * 8];
        float dtv = dtbT[(long)h * BROWS + rowg0 + l];
        u16x8 xv = *(const u16x8*)&rp[h * 64 + sg * 8];
#pragma unroll
        for (int jj = 0; jj < 8; ++jj)
            Xt[(sg * 8 + jj) * PADB + l] = f2bf(bf2f(xv[jj]) * dtv);
        *(u16x8*)&Sp[l * PADB + sg * 8] = *(const u16x8*)&sprev[spb + l * 64 + sg * 8];
    }
    __syncthreads();
    int w = t >> 6, lane = t & 63;
    int r16 = lane & 15, kg = lane >> 4;
    // phase 1: S = C.B^T (rows l in [16w,16w+16))
    bfx8 ac[2];
#pragma unroll
    for (int kk = 0; kk < 2; ++kk)
        ac[kk] = *(const bfx8*)&Cb[(w * 16 + r16) * PADB + kk * 32 + kg * 8];
    f32x4 s_acc[4] = {};
#pragma unroll
    for (int j = 0; j < 4; ++j)
#pragma unroll
        for (int kk = 0; kk < 2; ++kk) {
            bfx8 bb = *(const bfx8*)&Bb[(j * 16 + r16) * PADB + kk * 32 + kg * 8];
            s_acc[j] = __builtin_amdgcn_mfma_f32_16x16x32_bf16(ac[kk], bb, s_acc[j], 0, 0, 0);
        }
    // mask + decay -> Sm (bf16)
#pragma unroll
    for (int j = 0; j < 4; ++j)
#pragma unroll
        for (int q = 0; q < 4; ++q) {
            int l = w * 16 + kg * 4 + q;
            int s = j * 16 + r16;
            float v = s_acc[j][q];
            v = (s <= l) ? v * __expf(sAcs[l] - sAcs[s]) : 0.f;
            Sm[l * PADB + s] = f2bf(v);
        }
    __syncthreads();
    // phase 2: Yd = Sm @ xd;  phase 3: Yo = C @ Sprev^T
    bfx8 as[2];
#pragma unroll
    for (int kk = 0; kk < 2; ++kk)
        as[kk] = *(const bfx8*)&Sm[(w * 16 + r16) * PADB + kk * 32 + kg * 8];
    f32x4 d_acc[4] = {}, o_acc[4] = {};
#pragma unroll
    for (int j = 0; j < 4; ++j)
#pragma unroll
        for (int kk = 0; kk < 2; ++kk) {
            bfx8 xb = *(const bfx8*)&Xt[(j * 16 + r16) * PADB + kk * 32 + kg * 8];
            d_acc[j] = __builtin_amdgcn_mfma_f32_16x16x32_bf16(as[kk], xb, d_acc[j], 0, 0, 0);
            bfx8 sb = *(const bfx8*)&Sp[(j * 16 + r16) * PADB + kk * 32 + kg * 8];
            o_acc[j] = __builtin_amdgcn_mfma_f32_16x16x32_bf16(ac[kk], sb, o_acc[j], 0, 0, 0);
        }
    // epilogue tile -> Bb (dead), then coalesced copy out
#pragma unroll
    for (int j = 0; j < 4; ++j)
#pragma unroll
        for (int q = 0; q < 4; ++q) {
            int l = w * 16 + kg * 4 + q;
            int p = j * 16 + r16;
            Bb[l * PADB + p] = f2bf(d_acc[j][q] + sE[l] * o_acc[j][q]);
        }
    __syncthreads();
#pragma unroll
    for (int i = 0; i < 2; ++i) {
        int q = t + 256 * i;
        int l = q >> 3, sg = q & 7;
        *(u16x8*)&ybuf[(rowg0 + l) * (long)DINNER + h * 64 + sg * 8] =
            *(const u16x8*)&Bb[l * PADB + sg * 8];
    }
}

// ---- gated RMS norm -> bf16 ----
__global__ __launch_bounds__(256) void norm_kernel(const ushort_t* __restrict__ ybuf,
                                                   const ushort_t* __restrict__ xbc,
                                                   const ushort_t* __restrict__ zbf,
                                                   const float* __restrict__ Dp,
                                                   const float* __restrict__ normw,
                                                   ushort_t* __restrict__ ybf) {
    int row = blockIdx.x;
    int t = threadIdx.x;
    float g[6];
    float ss = 0.f;
#pragma unroll
    for (int i = 0; i < 6; ++i) {
        int j = t + 256 * i;
        int h = j >> 6;
        float x = bf2f(xbc[(long)row * XBCW + j]);
        float yy = bf2f(ybuf[(long)row * DINNER + j]) + x * Dp[h];
        float z = bf2f(zbf[(long)row * DINNER + j]);
        float gz = z / (1.f + __expf(-z));
        float v = yy * gz;
        g[i] = v;
        ss += v * v;
    }
#pragma unroll
    for (int o = 32; o > 0; o >>= 1) ss += __shfl_xor(ss, o, 64);
    __shared__ float wsum[4];
    __shared__ float sscale;
    int w = t >> 6;
    if ((t & 63) == 0) wsum[w] = ss;
    __syncthreads();
    if (t == 0) {
        float tot = wsum[0] + wsum[1] + wsum[2] + wsum[3];
        sscale = rsqrtf(tot / (float)DINNER + 1e-5f);
    }
    __syncthreads();
    float sc = sscale;
#pragma unroll
    for (int i = 0; i < 6; ++i) {
        int j = t + 256 * i;
        ybf[(long)row * DINNER + j] = f2bf(g[i] * sc * normw[j]);
    }
}

extern "C" void kernel_launch(void* const* d_in, const int* in_sizes, int n_in,
                              void* d_out, int out_size, void* d_ws, size_t ws_size,
                              hipStream_t stream) {
    const float* u = (const float*)d_in[0];
    const float* W_in = (const float*)d_in[1];
    const float* conv_w = (const float*)d_in[2];
    const float* conv_b = (const float*)d_in[3];
    const float* dt_bias = (const float*)d_in[4];
    const float* A_log = (const float*)d_in[5];
    const float* Dp = (const float*)d_in[6];
    const float* norm_w = (const float*)d_in[7];
    const float* W_out = (const float*)d_in[8];
    float* out = (float*)d_out;

    char* ws = (char*)d_ws;
    size_t off = 0;
    auto alloc = [&](size_t bytes) {
        void* p = ws + off;
        off += (bytes + 255) & ~(size_t)255;
        return p;
    };
    ushort_t* zbf = (ushort_t*)alloc((size_t)BROWS * DINNER * 2);      // 25.2 MB
    float* xbcraw = (float*)alloc((size_t)BROWS * XBCW * 4);           // 54.5 MB (f32, from gemm1)
    ushort_t* xbc = (ushort_t*)alloc((size_t)BROWS * XBCW * 2);        // 27.3 MB (bf16, from conv)
    float* dtbT = (float*)alloc((size_t)NH * BROWS * 4);               // 0.79 MB
    float* acs = (float*)alloc((size_t)2 * NH * NCHUNK * 64 * 4);      // 0.79 MB
    float* Tsum = (float*)alloc((size_t)2 * NH * NCHUNK * 4);          // 12 KB
    ushort_t* states = (ushort_t*)alloc((size_t)2 * NH * NCHUNK * 4096 * 2);  // 25.2 MB
    ushort_t* ybuf = (ushort_t*)alloc((size_t)BROWS * DINNER * 2);     // 25.2 MB
    // aliases with disjoint lifetimes:
    ushort_t* ybf = (ushort_t*)xbcraw;    // xbcraw dead after conv
    ushort_t* ubf = ybuf;                 // u-bf16 dead after gemm1; ybuf written in yfull
    ushort_t* winbf = states;             // W_in-bf16 dead after gemm1; states written after
    ushort_t* woutbf = states;            // W_out-bf16 written after yfull consumed states

    if (off > ws_size) {
        fill_kernel<<<(out_size + 255) / 256, 256, 0, stream>>>(out, out_size, 12345.0f);
        return;
    }

    // pre-convert inputs to bf16
    cvt_kernel<<<(BROWS * DM / 4 + 255) / 256, 256, 0, stream>>>(u, ubf, (long)BROWS * DM / 4);
    cvt_pad_kernel<<<((long)NPAD1 * 192 + 255) / 256, 256, 0, stream>>>(W_in, winbf);

    // in-projection with split epilogue (z bf16 / xBC f32 / dt softplus transposed)
    gemm_bt<1><<<dim3(26, 64), 256, 0, stream>>>(ubf, winbf, nullptr, DM, 0,
                                                 zbf, xbcraw, dtbT, dt_bias);

    conv_kernel<<<dim3(BROWS, 7), 256, 0, stream>>>(xbcraw, conv_w, conv_b, xbc);

    acs_kernel<<<2 * NH, 256, 0, stream>>>(dtbT, A_log, acs, Tsum);
    states_kernel<<<dim3(NH, NCHUNK, 2), 256, 0, stream>>>(xbc, dtbT, acs, Tsum, states);
    scan_kernel<<<dim3(16, NH, 2), 256, 0, stream>>>(Tsum, states);
    yfull_kernel<<<dim3(NH, NCHUNK, 2), 256, 0, stream>>>(xbc, dtbT, acs, states, ybuf);

    norm_kernel<<<BROWS, 256, 0, stream>>>(ybuf, xbc, zbf, Dp, norm_w, ybf);

    // W_out -> bf16 into states region (dead after yfull), then out-projection
    cvt_kernel<<<(DM * DINNER / 4 + 255) / 256, 256, 0, stream>>>(W_out, woutbf, (long)DM * DINNER / 4);
    gemm_bt<0><<<dim3(6, 64), 256, 0, stream>>>(ybf, woutbf, out, DINNER, DM,
                                                nullptr, nullptr, nullptr, nullptr);
}

// Round 15
// 278.691 us; speedup vs baseline: 7.0663x; 1.0055x over previous
//
#include <hip/hip_runtime.h>

typedef __attribute__((ext_vector_type(4))) float f4;
typedef __attribute__((ext_vector_type(8))) short bfx8;
typedef __attribute__((ext_vector_type(4))) float f32x4;
typedef __attribute__((ext_vector_type(4))) unsigned int u32x4;
typedef __attribute__((ext_vector_type(4))) unsigned short u16x4;
typedef __attribute__((ext_vector_type(8))) unsigned short u16x8;
typedef unsigned short ushort_t;

#define DM 768
#define DINNER 1536
#define NH 24
#define XBCW 1664
#define DINPROJ 3224
#define NPAD1 3328
#define NCHUNK 64
#define BROWS 8192
#define PADB 72  // bf16 LDS row stride for 64-wide tiles

__device__ inline ushort_t f2bf(float f) {
    unsigned u = __builtin_bit_cast(unsigned, f);
    unsigned r = (u + 0x7FFF + ((u >> 16) & 1)) >> 16;
    return (ushort_t)r;
}
__device__ inline float bf2f(ushort_t u) {
    return __builtin_bit_cast(float, (unsigned)u << 16);
}
// direct global->LDS 16B staging. dst wave-uniform; HW adds lane*16.
__device__ inline void gl16(const void* g, void* l) {
    __builtin_amdgcn_global_load_lds((const __attribute__((address_space(1))) void*)g,
                                     (__attribute__((address_space(3))) void*)l, 16, 0, 0);
}

__global__ __launch_bounds__(256) void fill_kernel(float* out, int n, float v) {
    int i = blockIdx.x * 256 + threadIdx.x;
    if (i < n) out[i] = v;
}

// ---- f32 -> bf16 bulk convert ----
__global__ __launch_bounds__(256) void cvt_kernel(const float* __restrict__ in,
                                                  ushort_t* __restrict__ outp, long n4) {
    long i = (long)blockIdx.x * 256 + threadIdx.x;
    if (i >= n4) return;
    f4 v = *(const f4*)&in[i * 4];
    u16x4 o;
    o[0] = f2bf(v[0]); o[1] = f2bf(v[1]); o[2] = f2bf(v[2]); o[3] = f2bf(v[3]);
    *(u16x4*)&outp[i * 4] = o;
}

// ---- W_in f32 [3224][768] -> bf16 [3328][768], zero-padded rows ----
__global__ __launch_bounds__(256) void cvt_pad_kernel(const float* __restrict__ in,
                                                      ushort_t* __restrict__ outp) {
    long q = (long)blockIdx.x * 256 + threadIdx.x;
    if (q >= (long)NPAD1 * 192) return;
    int row = (int)(q / 192);
    int cq = (int)(q % 192);
    u16x4 o = {0, 0, 0, 0};
    if (row < DINPROJ) {
        f4 v = *(const f4*)&in[(long)row * DM + cq * 4];
        o[0] = f2bf(v[0]); o[1] = f2bf(v[1]); o[2] = f2bf(v[2]); o[3] = f2bf(v[3]);
    }
    *(u16x4*)&outp[q * 4] = o;
}

// ---- GEMM C = A[M][K] * B[N][K]^T, bf16 in, 3-buffer 2-deep counted-vmcnt pipeline.
// EPI=0: C f32 dense (out-proj). EPI=1: split epilogue (in-proj, xBC -> bf16).
template <int EPI>
__global__ __launch_bounds__(256) void gemm_bt(const ushort_t* __restrict__ A,
                                               const ushort_t* __restrict__ B,
                                               float* __restrict__ C,
                                               int K, int ldc,
                                               ushort_t* __restrict__ zbf,
                                               ushort_t* __restrict__ xbcbf,
                                               float* __restrict__ dtbT,
                                               const float* __restrict__ dt_bias) {
    __shared__ __align__(16) ushort_t As[3][128 * 32];  // 8KB each
    __shared__ __align__(16) ushort_t Bs[3][128 * 32];
    int tid = threadIdx.x;
    int lane = tid & 63;
    int w = tid >> 6;
    int wr = w >> 1, wc = w & 1;
    int m0 = blockIdx.y * 128;
    int n0 = blockIdx.x * 128;
    int r16 = lane & 15, kg = lane >> 4;

    int row0 = tid >> 2, cof0 = (tid & 3) * 8;
    const ushort_t* a0 = &A[(long)(m0 + row0) * K + cof0];
    const ushort_t* a1 = &A[(long)(m0 + row0 + 64) * K + cof0];
    const ushort_t* b0 = &B[(long)(n0 + row0) * K + cof0];
    const ushort_t* b1 = &B[(long)(n0 + row0 + 64) * K + cof0];
    char* asb[3] = {(char*)&As[0][0] + w * 1024, (char*)&As[1][0] + w * 1024,
                    (char*)&As[2][0] + w * 1024};
    char* bsb[3] = {(char*)&Bs[0][0] + w * 1024, (char*)&Bs[1][0] + w * 1024,
                    (char*)&Bs[2][0] + w * 1024};

    f32x4 acc[4][4] = {};
    int nk = K >> 5;

    auto issue = [&](int t) {
        int k = t << 5;
        int bi = t % 3;
        gl16(a0 + k, asb[bi]); gl16(a1 + k, asb[bi] + 4096);
        gl16(b0 + k, bsb[bi]); gl16(b1 + k, bsb[bi] + 4096);
    };
    issue(0);
    issue(1);

    for (int t = 0; t < nk; ++t) {
        if (t + 1 < nk) {  // tile t+1's 4 loads may stay in flight
            asm volatile("s_waitcnt vmcnt(4)" ::: "memory");
        } else {
            asm volatile("s_waitcnt vmcnt(0)" ::: "memory");
        }
        __builtin_amdgcn_s_barrier();   // tile t visible to all; compute(t-1) reads done
        __builtin_amdgcn_sched_barrier(0);
        if (t + 2 < nk) issue(t + 2);   // overwrites buf((t-1)%3) — safe after barrier
        const ushort_t* Asc = &As[t % 3][0];
        const ushort_t* Bsc = &Bs[t % 3][0];
        bfx8 af[4], bfr[4];
#pragma unroll
        for (int i = 0; i < 4; ++i) {
            af[i] = *(const bfx8*)&Asc[(wr * 64 + i * 16 + r16) * 32 + kg * 8];
            bfr[i] = *(const bfx8*)&Bsc[(wc * 64 + i * 16 + r16) * 32 + kg * 8];
        }
#pragma unroll
        for (int i = 0; i < 4; ++i)
#pragma unroll
            for (int j = 0; j < 4; ++j)
                acc[i][j] = __builtin_amdgcn_mfma_f32_16x16x32_bf16(af[i], bfr[j], acc[i][j], 0, 0, 0);
    }

#pragma unroll
    for (int i = 0; i < 4; ++i) {
        int rowb = m0 + wr * 64 + i * 16 + kg * 4;
#pragma unroll
        for (int j = 0; j < 4; ++j) {
            int col = n0 + wc * 64 + j * 16 + r16;
            if (EPI == 0) {
#pragma unroll
                for (int q = 0; q < 4; ++q)
                    C[(long)(rowb + q) * ldc + col] = acc[i][j][q];
            } else {
                if (n0 < DINNER) {  // z -> bf16
#pragma unroll
                    for (int q = 0; q < 4; ++q)
                        zbf[(long)(rowb + q) * DINNER + col] = f2bf(acc[i][j][q]);
                } else if (n0 < 3200) {  // xBC raw -> bf16
#pragma unroll
                    for (int q = 0; q < 4; ++q)
                        xbcbf[(long)(rowb + q) * XBCW + col - DINNER] = f2bf(acc[i][j][q]);
                } else if (col < DINPROJ) {  // dt -> softplus -> transposed
                    int h = col - 3200;
                    float bias = dt_bias[h];
#pragma unroll
                    for (int q = 0; q < 4; ++q) {
                        float v = acc[i][j][q] + bias;
                        float d = (v > 20.f) ? v : log1pf(__expf(v));
                        dtbT[(long)h * BROWS + rowb + q] = d;
                    }
                }
            }
        }
    }
}

// ---- depthwise causal conv(4) + bias + silu; bf16 in, bf16 out ----
__global__ __launch_bounds__(256) void conv_kernel(const ushort_t* __restrict__ xin,
                                                   const float* __restrict__ cw,
                                                   const float* __restrict__ cb,
                                                   ushort_t* __restrict__ xbc) {
    int ch = blockIdx.y * 256 + threadIdx.x;
    int row = blockIdx.x;
    if (ch >= XBCW) return;
    int b = row >> 12;
    int l = row & 4095;
    float acc = cb[ch];
#pragma unroll
    for (int k = 0; k < 4; ++k) {
        int ll = l - 3 + k;
        if (ll >= 0)
            acc += cw[ch * 4 + k] * bf2f(xin[(long)(b * 4096 + ll) * XBCW + ch]);
    }
    float s = acc / (1.f + __expf(-acc));
    xbc[(long)row * XBCW + ch] = f2bf(s);
}

// ---- per-chunk cumsum of A*dt via wave scan ----
__global__ __launch_bounds__(256) void acs_kernel(const float* __restrict__ dtbT,
                                                  const float* __restrict__ A_log,
                                                  float* __restrict__ acs,
                                                  float* __restrict__ Tsum) {
    int bh = blockIdx.x;
    int b = bh / NH, h = bh % NH;
    int t = threadIdx.x;
    int lane = t & 63;
    float A = -__expf(A_log[h]);
    const float* dp = &dtbT[(long)h * BROWS + b * 4096];
#pragma unroll
    for (int it = 0; it < 16; ++it) {
        int c = (t >> 6) + 4 * it;
        float v = A * dp[c * 64 + lane];
#pragma unroll
        for (int off = 1; off < 64; off <<= 1) {
            float u = __shfl_up(v, off, 64);
            if (lane >= off) v += u;
        }
        acs[((long)bh * NCHUNK + c) * 64 + lane] = v;
        if (lane == 63) Tsum[bh * NCHUNK + c] = v;
    }
}

// ---- phase A (MFMA): states[p][n] = sum_l (x*dt*decay)[l][p] * B[l][n] -> bf16 ----
__global__ __launch_bounds__(256) void states_kernel(const ushort_t* __restrict__ xbc,
                                                     const float* __restrict__ dtbT,
                                                     const float* __restrict__ acs,
                                                     const float* __restrict__ Tsum,
                                                     ushort_t* __restrict__ states) {
    int h = blockIdx.x, c = blockIdx.y, b = blockIdx.z;
    __shared__ __align__(16) ushort_t Wt[64 * PADB];
    __shared__ __align__(16) ushort_t Bt[64 * PADB];
    int t = threadIdx.x;
    long rowg0 = (long)b * 4096 + c * 64;
    long acsb = ((long)(b * NH + h) * NCHUNK + c) * 64;
    float T = Tsum[(b * NH + h) * NCHUNK + c];
#pragma unroll
    for (int i = 0; i < 2; ++i) {
        int q = t + 256 * i;
        int l = q >> 3, sg = q & 7;
        const ushort_t* rp = &xbc[(rowg0 + l) * (long)XBCW];
        float dec = dtbT[(long)h * BROWS + rowg0 + l] * __expf(T - acs[acsb + l]);
        u16x8 xv = *(const u16x8*)&rp[h * 64 + sg * 8];
        u16x8 bv = *(const u16x8*)&rp[DINNER + sg * 8];
#pragma unroll
        for (int jj = 0; jj < 8; ++jj) {
            Wt[(sg * 8 + jj) * PADB + l] = f2bf(bf2f(xv[jj]) * dec);
            Bt[(sg * 8 + jj) * PADB + l] = bv[jj];
        }
    }
    __syncthreads();
    int w = t >> 6, lane = t & 63;
    int r16 = lane & 15, kg = lane >> 4;
    bfx8 aw[2];
#pragma unroll
    for (int kk = 0; kk < 2; ++kk)
        aw[kk] = *(const bfx8*)&Wt[(w * 16 + r16) * PADB + kk * 32 + kg * 8];
    f32x4 acc[4] = {};
#pragma unroll
    for (int j = 0; j < 4; ++j)
#pragma unroll
        for (int kk = 0; kk < 2; ++kk) {
            bfx8 bb = *(const bfx8*)&Bt[(j * 16 + r16) * PADB + kk * 32 + kg * 8];
            acc[j] = __builtin_amdgcn_mfma_f32_16x16x32_bf16(aw[kk], bb, acc[j], 0, 0, 0);
        }
    __syncthreads();
#pragma unroll
    for (int j = 0; j < 4; ++j)
#pragma unroll
        for (int q = 0; q < 4; ++q)
            Wt[(w * 16 + kg * 4 + q) * PADB + j * 16 + r16] = f2bf(acc[j][q]);
    __syncthreads();
    long ob = ((long)(b * NH + h) * NCHUNK + c) * 4096;
#pragma unroll
    for (int i = 0; i < 2; ++i) {
        int q = t + 256 * i;
        int p = q >> 3, sg = q & 7;
        *(u16x8*)&states[ob + p * 64 + sg * 8] = *(const u16x8*)&Wt[p * PADB + sg * 8];
    }
}

// ---- sequential chunk scan ----
__global__ __launch_bounds__(256) void scan_kernel(const float* __restrict__ Tsum,
                                                   ushort_t* __restrict__ states) {
    int e = blockIdx.x * 256 + threadIdx.x;
    int h = blockIdx.y, b = blockIdx.z;
    long base = ((long)(b * NH + h)) * NCHUNK * 4096 + e;
    const float* Tp = &Tsum[(b * NH + h) * NCHUNK];
    float acc = 0.f;
    for (int c = 0; c < NCHUNK; ++c) {
        float cur = bf2f(states[base + (long)c * 4096]);
        states[base + (long)c * 4096] = f2bf(acc);
        acc = __expf(Tp[c]) * acc + cur;
    }
}

// ---- phase C (MFMA): Y = (C.B^T . Lm) @ xd + exp(acs) * (C @ Sprev^T) -> bf16 ybuf ----
__global__ __launch_bounds__(256) void yfull_kernel(const ushort_t* __restrict__ xbc,
                                                    const float* __restrict__ dtbT,
                                                    const float* __restrict__ acs,
                                                    const ushort_t* __restrict__ sprev,
                                                    ushort_t* __restrict__ ybuf) {
    int h = blockIdx.x, c = blockIdx.y, b = blockIdx.z;
    __shared__ __align__(16) ushort_t Cb[64 * PADB];  // C[l][n]
    __shared__ __align__(16) ushort_t Bb[64 * PADB];  // B[s][n], later output tile [l][p]
    __shared__ __align__(16) ushort_t Xt[64 * PADB];  // xd^T[p][s]
    __shared__ __align__(16) ushort_t Sp[64 * PADB];  // sprev[p][n]
    __shared__ __align__(16) ushort_t Sm[64 * PADB];  // masked scores [l][s]
    __shared__ float sAcs[64], sE[64];
    int t = threadIdx.x;
    long rowg0 = (long)b * 4096 + c * 64;
    long acsb = ((long)(b * NH + h) * NCHUNK + c) * 64;
    long spb = ((long)(b * NH + h) * NCHUNK + c) * 4096;
    if (t < 64) {
        float a = acs[acsb + t];
        sAcs[t] = a;
        sE[t] = __expf(a);
    }
#pragma unroll
    for (int i = 0; i < 2; ++i) {
        int q = t + 256 * i;
        int l = q >> 3, sg = q & 7;
        const ushort_t* rp = &xbc[(rowg0 + l) * (long)XBCW];
        *(u16x8*)&Cb[l * PADB + sg * 8] = *(const u16x8*)&rp[1600 + sg * 8];
        *(u16x8*)&Bb[l * PADB + sg * 8] = *(const u16x8*)&rp[DINNER + sg * 8];
        float dtv = dtbT[(long)h * BROWS + rowg0 + l];
        u16x8 xv = *(const u16x8*)&rp[h * 64 + sg * 8];
#pragma unroll
        for (int jj = 0; jj < 8; ++jj)
            Xt[(sg * 8 + jj) * PADB + l] = f2bf(bf2f(xv[jj]) * dtv);
        *(u16x8*)&Sp[l * PADB + sg * 8] = *(const u16x8*)&sprev[spb + l * 64 + sg * 8];
    }
    __syncthreads();
    int w = t >> 6, lane = t & 63;
    int r16 = lane & 15, kg = lane >> 4;
    // phase 1: S = C.B^T (rows l in [16w,16w+16))
    bfx8 ac[2];
#pragma unroll
    for (int kk = 0; kk < 2; ++kk)
        ac[kk] = *(const bfx8*)&Cb[(w * 16 + r16) * PADB + kk * 32 + kg * 8];
    f32x4 s_acc[4] = {};
#pragma unroll
    for (int j = 0; j < 4; ++j)
#pragma unroll
        for (int kk = 0; kk < 2; ++kk) {
            bfx8 bb = *(const bfx8*)&Bb[(j * 16 + r16) * PADB + kk * 32 + kg * 8];
            s_acc[j] = __builtin_amdgcn_mfma_f32_16x16x32_bf16(ac[kk], bb, s_acc[j], 0, 0, 0);
        }
    // mask + decay -> Sm (bf16)
#pragma unroll
    for (int j = 0; j < 4; ++j)
#pragma unroll
        for (int q = 0; q < 4; ++q) {
            int l = w * 16 + kg * 4 + q;
            int s = j * 16 + r16;
            float v = s_acc[j][q];
            v = (s <= l) ? v * __expf(sAcs[l] - sAcs[s]) : 0.f;
            Sm[l * PADB + s] = f2bf(v);
        }
    __syncthreads();
    // phase 2: Yd = Sm @ xd;  phase 3: Yo = C @ Sprev^T
    bfx8 as[2];
#pragma unroll
    for (int kk = 0; kk < 2; ++kk)
        as[kk] = *(const bfx8*)&Sm[(w * 16 + r16) * PADB + kk * 32 + kg * 8];
    f32x4 d_acc[4] = {}, o_acc[4] = {};
#pragma unroll
    for (int j = 0; j < 4; ++j)
#pragma unroll
        for (int kk = 0; kk < 2; ++kk) {
            bfx8 xb = *(const bfx8*)&Xt[(j * 16 + r16) * PADB + kk * 32 + kg * 8];
            d_acc[j] = __builtin_amdgcn_mfma_f32_16x16x32_bf16(as[kk], xb, d_acc[j], 0, 0, 0);
            bfx8 sb = *(const bfx8*)&Sp[(j * 16 + r16) * PADB + kk * 32 + kg * 8];
            o_acc[j] = __builtin_amdgcn_mfma_f32_16x16x32_bf16(ac[kk], sb, o_acc[j], 0, 0, 0);
        }
    // epilogue tile -> Bb (dead), then coalesced copy out
#pragma unroll
    for (int j = 0; j < 4; ++j)
#pragma unroll
        for (int q = 0; q < 4; ++q) {
            int l = w * 16 + kg * 4 + q;
            int p = j * 16 + r16;
            Bb[l * PADB + p] = f2bf(d_acc[j][q] + sE[l] * o_acc[j][q]);
        }
    __syncthreads();
#pragma unroll
    for (int i = 0; i < 2; ++i) {
        int q = t + 256 * i;
        int l = q >> 3, sg = q & 7;
        *(u16x8*)&ybuf[(rowg0 + l) * (long)DINNER + h * 64 + sg * 8] =
            *(const u16x8*)&Bb[l * PADB + sg * 8];
    }
}

// ---- gated RMS norm -> bf16 ----
__global__ __launch_bounds__(256) void norm_kernel(const ushort_t* __restrict__ ybuf,
                                                   const ushort_t* __restrict__ xbc,
                                                   const ushort_t* __restrict__ zbf,
                                                   const float* __restrict__ Dp,
                                                   const float* __restrict__ normw,
                                                   ushort_t* __restrict__ ybf) {
    int row = blockIdx.x;
    int t = threadIdx.x;
    float g[6];
    float ss = 0.f;
#pragma unroll
    for (int i = 0; i < 6; ++i) {
        int j = t + 256 * i;
        int h = j >> 6;
        float x = bf2f(xbc[(long)row * XBCW + j]);
        float yy = bf2f(ybuf[(long)row * DINNER + j]) + x * Dp[h];
        float z = bf2f(zbf[(long)row * DINNER + j]);
        float gz = z / (1.f + __expf(-z));
        float v = yy * gz;
        g[i] = v;
        ss += v * v;
    }
#pragma unroll
    for (int o = 32; o > 0; o >>= 1) ss += __shfl_xor(ss, o, 64);
    __shared__ float wsum[4];
    __shared__ float sscale;
    int w = t >> 6;
    if ((t & 63) == 0) wsum[w] = ss;
    __syncthreads();
    if (t == 0) {
        float tot = wsum[0] + wsum[1] + wsum[2] + wsum[3];
        sscale = rsqrtf(tot / (float)DINNER + 1e-5f);
    }
    __syncthreads();
    float sc = sscale;
#pragma unroll
    for (int i = 0; i < 6; ++i) {
        int j = t + 256 * i;
        ybf[(long)row * DINNER + j] = f2bf(g[i] * sc * normw[j]);
    }
}

extern "C" void kernel_launch(void* const* d_in, const int* in_sizes, int n_in,
                              void* d_out, int out_size, void* d_ws, size_t ws_size,
                              hipStream_t stream) {
    const float* u = (const float*)d_in[0];
    const float* W_in = (const float*)d_in[1];
    const float* conv_w = (const float*)d_in[2];
    const float* conv_b = (const float*)d_in[3];
    const float* dt_bias = (const float*)d_in[4];
    const float* A_log = (const float*)d_in[5];
    const float* Dp = (const float*)d_in[6];
    const float* norm_w = (const float*)d_in[7];
    const float* W_out = (const float*)d_in[8];
    float* out = (float*)d_out;

    char* ws = (char*)d_ws;
    size_t off = 0;
    auto alloc = [&](size_t bytes) {
        void* p = ws + off;
        off += (bytes + 255) & ~(size_t)255;
        return p;
    };
    ushort_t* zbf = (ushort_t*)alloc((size_t)BROWS * DINNER * 2);      // 25.2 MB
    ushort_t* xbcrawbf = (ushort_t*)alloc((size_t)BROWS * XBCW * 2);   // 27.3 MB (bf16, from gemm1)
    ushort_t* xbc = (ushort_t*)alloc((size_t)BROWS * XBCW * 2);        // 27.3 MB (bf16, from conv)
    float* dtbT = (float*)alloc((size_t)NH * BROWS * 4);               // 0.79 MB
    float* acs = (float*)alloc((size_t)2 * NH * NCHUNK * 64 * 4);      // 0.79 MB
    float* Tsum = (float*)alloc((size_t)2 * NH * NCHUNK * 4);          // 12 KB
    ushort_t* states = (ushort_t*)alloc((size_t)2 * NH * NCHUNK * 4096 * 2);  // 25.2 MB
    ushort_t* ybuf = (ushort_t*)alloc((size_t)BROWS * DINNER * 2);     // 25.2 MB
    // aliases with disjoint lifetimes:
    ushort_t* ybf = xbcrawbf;             // xbcrawbf dead after conv; 25.2MB <= 27.3MB
    ushort_t* ubf = ybuf;                 // u-bf16 dead after gemm1; ybuf written in yfull
    ushort_t* winbf = states;             // W_in-bf16 dead after gemm1; states written after
    ushort_t* woutbf = states;            // W_out-bf16 written after yfull consumed states

    if (off > ws_size) {
        fill_kernel<<<(out_size + 255) / 256, 256, 0, stream>>>(out, out_size, 12345.0f);
        return;
    }

    // pre-convert inputs to bf16
    cvt_kernel<<<(BROWS * DM / 4 + 255) / 256, 256, 0, stream>>>(u, ubf, (long)BROWS * DM / 4);
    cvt_pad_kernel<<<((long)NPAD1 * 192 + 255) / 256, 256, 0, stream>>>(W_in, winbf);

    // in-projection with split epilogue (z bf16 / xBC bf16 / dt softplus transposed)
    gemm_bt<1><<<dim3(26, 64), 256, 0, stream>>>(ubf, winbf, nullptr, DM, 0,
                                                 zbf, xbcrawbf, dtbT, dt_bias);

    conv_kernel<<<dim3(BROWS, 7), 256, 0, stream>>>(xbcrawbf, conv_w, conv_b, xbc);

    acs_kernel<<<2 * NH, 256, 0, stream>>>(dtbT, A_log, acs, Tsum);
    states_kernel<<<dim3(NH, NCHUNK, 2), 256, 0, stream>>>(xbc, dtbT, acs, Tsum, states);
    scan_kernel<<<dim3(16, NH, 2), 256, 0, stream>>>(Tsum, states);
    yfull_kernel<<<dim3(NH, NCHUNK, 2), 256, 0, stream>>>(xbc, dtbT, acs, states, ybuf);

    norm_kernel<<<BROWS, 256, 0, stream>>>(ybuf, xbc, zbf, Dp, norm_w, ybf);

    // W_out -> bf16 into states region (dead after yfull), then out-projection
    cvt_kernel<<<(DM * DINNER / 4 + 255) / 256, 256, 0, stream>>>(W_out, woutbf, (long)DM * DINNER / 4);
    gemm_bt<0><<<dim3(6, 64), 256, 0, stream>>>(ybf, woutbf, out, DINNER, DM,
                                                nullptr, nullptr, nullptr, nullptr);
}